// Round 3
// baseline (983.755 us; speedup 1.0000x reference)
//
#include <hip/hip_runtime.h>
#include <hip/hip_cooperative_groups.h>

namespace cg = cooperative_groups;

// ---------------------------------------------------------------------------
// GCN pipeline, round 27: ONE cooperative mega-kernel (hist -> scan ->
// multisplit -> place -> agg1 -> agg2 separated by grid.sync()), with the
// proven r26 six-kernel path as a runtime fallback.
// r25/r26 lesson: three structurally different sort stages all measured
// 176.6-179.5us -- per-kernel optimization is invisible, implying the time
// is diffuse boundary overhead (6 launches x ramp/drain) and/or a harness
// floor. The mega-kernel removes 5 boundaries AND forces the real pipeline
// into the rocprof top-5 window for the first time.
// ---------------------------------------------------------------------------

#define MS_TILE 2048
#define MAXB 512  // padded coarse-bucket count (NBkt = ceil(n/256) <= 512)
#define AGG_NODES 32
#define AGG_STAGE 1024
#define PF_T 512   // fallback place_fine2 threads
#define PF_EPT 10
#define PF_OV 1024
#define SMEM_BYTES 18688  // max over phases (agg1: 18688; multisplit: 18452)

typedef __attribute__((ext_vector_type(4))) _Float16 half4;
typedef __attribute__((ext_vector_type(8))) _Float16 half8;

// Inclusive shfl scan across 4 waves; cross-wave combine via wsum[4].
__device__ inline int scan256_incl(int v, int lane, int w, int* wsum,
                                   int* total) {
    int incl = v;
#pragma unroll
    for (int d = 1; d < 64; d <<= 1) {
        int up = __shfl_up(incl, d, 64);
        if (lane >= d) incl += up;
    }
    if (lane == 63) wsum[w] = incl;
    __syncthreads();
    int add = 0;
    if (w > 0) add += wsum[0];
    if (w > 1) add += wsum[1];
    if (w > 2) add += wsum[2];
    *total = wsum[0] + wsum[1] + wsum[2] + wsum[3];
    return incl + add;
}

struct MegaArgs {
    const int* src;
    const int* dst;
    const float* x;
    const float* W1;
    const float* b1;
    const float* W2;
    const float* b2v;
    const float* fcW1;
    const float* fcb1;
    const float* fcW2;
    const float* fcb2;
    float* out;
    int* histG;
    int* offsG;
    int* btot;
    int* gbase;
    int* offs;
    float* dinv;
    _Float16* y;
    int* srcs;
    unsigned* binned;
    _Float16* h2;
    int n, E, nTiles;
};

__global__ __launch_bounds__(256, 4) void mega(MegaArgs a) {
    extern __shared__ char smem[];
    cg::grid_group g = cg::this_grid();
    int t = threadIdx.x;
    int lane = t & 63, w = t >> 6;
    int nB = gridDim.x;

    // ------------------ phase 1: per-tile histogram ------------------
    {
        int* h = (int*)smem;
        for (int tile = blockIdx.x; tile < a.nTiles; tile += nB) {
            h[t] = 0;
            h[t + 256] = 0;
            __syncthreads();
            int base = tile * MS_TILE;
            int cnt = min(MS_TILE, a.E - base);
            for (int k = t; k < cnt; k += 256)
                atomicAdd(&h[a.dst[base + k] >> 8], 1);
            __syncthreads();
            a.histG[tile * MAXB + t] = h[t];
            a.histG[tile * MAXB + 256 + t] = h[t + 256];
            __syncthreads();
        }
    }
    __threadfence();
    g.sync();

    // ------------------ phase 2: tile-offset scan (transposed) -------
    {
        int(*lds)[66] = (int(*)[66])smem;
        int rr = t >> 2, bb = t & 3;  // 256 threads cover 64 rows x 4 buckets
        for (int bg = blockIdx.x; bg < MAXB / 4; bg += nB) {
            int B0 = bg * 4;
            int carry = 0;
            for (int c0 = 0; c0 < a.nTiles; c0 += 64) {
                int rows = min(64, a.nTiles - c0);
                int v = 0;
                if (rr < rows) v = a.histG[(c0 + rr) * MAXB + B0 + bb];
                lds[bb][rr] = v;
                __syncthreads();
                int x = lds[w][lane];
                int incl = x;
#pragma unroll
                for (int d = 1; d < 64; d <<= 1) {
                    int up = __shfl_up(incl, d, 64);
                    if (lane >= d) incl += up;
                }
                int total = __shfl(incl, 63, 64);
                lds[w][lane] = incl - x + carry;
                carry += total;
                __syncthreads();
                if (rr < rows)
                    a.offsG[(c0 + rr) * MAXB + B0 + bb] = lds[bb][rr];
                __syncthreads();
            }
            if (lane == 0) a.btot[B0 + w] = carry;
            __syncthreads();
        }
    }
    __threadfence();
    g.sync();

    // ------------------ phase 3: multisplit counting sort ------------
    {
        unsigned* stage = (unsigned*)smem;                   // 2048 u32
        unsigned short* sb = (unsigned short*)(smem + 8192); // 2048 u16
        int* hoff = (int*)(smem + 12288);                    // 513
        int* hcur = (int*)(smem + 14340);                    // 512
        int* gb = (int*)(smem + 16388);                      // 512
        int* wsum = (int*)(smem + 18436);                    // 4

        // hoisted bucket-base scan (tile-invariant)
        int b0v = a.btot[2 * t], b1v = a.btot[2 * t + 1];
        int s2 = b0v + b1v;
        int tot2;
        int incl2 = scan256_incl(s2, lane, w, wsum, &tot2);
        int ex2 = incl2 - s2;
        if (blockIdx.x == 0) {
            a.gbase[2 * t] = ex2;
            a.gbase[2 * t + 1] = ex2 + b0v;
            if (t == 255) a.gbase[MAXB] = a.E;
        }
        __syncthreads();

        for (int tile = blockIdx.x; tile < a.nTiles; tile += nB) {
            int base = tile * MS_TILE;
            int cnt = min(MS_TILE, a.E - base);
            gb[2 * t] = ex2 + a.offsG[tile * MAXB + 2 * t];
            gb[2 * t + 1] = ex2 + b0v + a.offsG[tile * MAXB + 2 * t + 1];
            int a0 = a.histG[tile * MAXB + 2 * t];
            int a1 = a.histG[tile * MAXB + 2 * t + 1];
            int s = a0 + a1;
            int tot;
            int incl = scan256_incl(s, lane, w, wsum, &tot);
            int ex = incl - s;
            hoff[2 * t] = ex;
            hoff[2 * t + 1] = ex + a0;
            hcur[2 * t] = ex;
            hcur[2 * t + 1] = ex + a0;
            if (t == 255) hoff[MAXB] = cnt;
            __syncthreads();
            for (int k = t; k < cnt; k += 256) {
                int d = a.dst[base + k];
                int b = d >> 8;
                int p = atomicAdd(&hcur[b], 1);
                stage[p] = ((unsigned)a.src[base + k] << 8) | (unsigned)(d & 255);
                sb[p] = (unsigned short)b;
            }
            __syncthreads();
            for (int k = t; k < cnt; k += 256) {
                int b = sb[k];
                a.binned[gb[b] + (k - hoff[b])] = stage[k];
            }
            __syncthreads();
        }
    }
    __threadfence();
    g.sync();

    // ------------------ phase 4: place (2-pass, per bucket) ----------
    {
        int* cnt = (int*)smem;            // 256
        int* lcur = (int*)(smem + 1024);  // 256
        int* wsum = (int*)(smem + 2048);  // 4
        int NBkt = (a.n + 255) >> 8;
        for (int b = blockIdx.x; b < NBkt; b += nB) {
            int node0 = b << 8;
            int nn = min(256, a.n - node0);
            int e0 = a.gbase[b], e1 = a.gbase[b + 1];
            cnt[t] = 0;
            __syncthreads();
            for (int k = e0 + t; k < e1; k += 256)
                atomicAdd(&cnt[a.binned[k] & 255u], 1);
            __syncthreads();
            int c = cnt[t];
            int tot;
            int incl = scan256_incl(c, lane, w, wsum, &tot);
            int myoff = e0 + (incl - c);
            lcur[t] = myoff;
            if (t < nn) {
                int node = node0 + t;
                a.offs[node] = myoff;
                float di = 1.0f / sqrtf((float)(c + 1));  // +1 self loop
                a.dinv[node] = di;
                const float* xr = a.x + (size_t)node * 5;
                half8 hv;
                hv[0] = (_Float16)(xr[0] * di);
                hv[1] = (_Float16)(xr[1] * di);
                hv[2] = (_Float16)(xr[2] * di);
                hv[3] = (_Float16)(xr[3] * di);
                hv[4] = (_Float16)(xr[4] * di);
                hv[5] = (_Float16)0.f;
                hv[6] = (_Float16)0.f;
                hv[7] = (_Float16)0.f;
                *(half8*)(a.y + (size_t)node * 8) = hv;
            }
            __syncthreads();
            for (int k = e0 + t; k < e1; k += 256) {
                unsigned wd = a.binned[k];
                int p = atomicAdd(&lcur[wd & 255u], 1);
                a.srcs[p] = (int)(wd >> 8);
            }
            __syncthreads();
        }
    }
    __threadfence();
    g.sync();

    // ------------------ phase 5: agg1 + W1/relu/W2 -------------------
    {
        float* w1s = (float*)smem;             // 320
        float* b1s = (float*)(smem + 1280);    // 64
        float* w2s = (float*)(smem + 1536);    // 2048
        float* o1 = (float*)(smem + 9728);     // 2048
        float* zs = (float*)(smem + 17920);    // 192
        w1s[t] = a.W1[t];
        if (t < 64) {
            w1s[t + 256] = a.W1[t + 256];
            b1s[t] = a.b1[t];
        }
#pragma unroll
        for (int r = 0; r < 8; ++r) w2s[r * 256 + t] = a.W2[r * 256 + t];
        __syncthreads();

        int li = t >> 3, e = t & 7;
        const half8* yv = (const half8*)a.y;
        for (int node0 = blockIdx.x * 32; node0 < a.n; node0 += nB * 32) {
            int i = node0 + li;
            float a0 = 0.f, a1 = 0.f, a2 = 0.f, a3 = 0.f, a4 = 0.f;
            if (i < a.n) {
                int off = a.offs[i];
                int cnt = ((i + 1 < a.n) ? a.offs[i + 1] : a.E) - off;
                if (e == 0) {  // self-loop term once per node
                    half8 v = yv[i];
                    a0 = (float)v[0]; a1 = (float)v[1]; a2 = (float)v[2];
                    a3 = (float)v[3]; a4 = (float)v[4];
                }
                for (int p = e; p < cnt; p += 8) {
                    half8 v = yv[a.srcs[off + p]];
                    a0 += (float)v[0]; a1 += (float)v[1]; a2 += (float)v[2];
                    a3 += (float)v[3]; a4 += (float)v[4];
                }
            }
#pragma unroll
            for (int m = 4; m >= 1; m >>= 1) {
                a0 += __shfl_xor(a0, m, 64);
                a1 += __shfl_xor(a1, m, 64);
                a2 += __shfl_xor(a2, m, 64);
                a3 += __shfl_xor(a3, m, 64);
                a4 += __shfl_xor(a4, m, 64);
            }
            if (i < a.n && e == 0) {
                float di = a.dinv[i];
                zs[li * 6 + 0] = a0 * di;
                zs[li * 6 + 1] = a1 * di;
                zs[li * 6 + 2] = a2 * di;
                zs[li * 6 + 3] = a3 * di;
                zs[li * 6 + 4] = a4 * di;
                zs[li * 6 + 5] = di;
            }
            __syncthreads();
#pragma unroll
            for (int r = 0; r < 8; ++r) {
                int idx = r * 256 + t;
                int lj = idx >> 6, f = idx & 63;
                if (node0 + lj < a.n) {
                    const float* zr = zs + lj * 6;
                    float acc = b1s[f];
#pragma unroll
                    for (int k = 0; k < 5; ++k) acc += zr[k] * w1s[k * 64 + f];
                    o1[lj * 64 + f] = fmaxf(acc, 0.0f);
                }
            }
            __syncthreads();
#pragma unroll
            for (int r = 0; r < 4; ++r) {
                int idx = r * 256 + t;
                int lj = idx >> 5, gg = idx & 31;
                int i2 = node0 + lj;
                if (i2 < a.n) {
                    float acc = 0.f;
#pragma unroll
                    for (int k = 0; k < 64; ++k)
                        acc += o1[lj * 64 + k] * w2s[k * 32 + gg];
                    a.h2[(size_t)i2 * 32 + gg] = (_Float16)(acc * zs[lj * 6 + 5]);
                }
            }
            __syncthreads();
        }
    }
    __threadfence();
    g.sync();

    // ------------------ phase 6: agg2 + FC head ----------------------
    {
        int* sidx = (int*)smem;               // 1024
        float* sm = (float*)(smem + 4096);    // 1056
        float* x3s = (float*)(smem + 8320);   // 512
        float* w1s = (float*)(smem + 10368);  // 512
        float* w2s = (float*)(smem + 12416);  // 32
        float* b1s = (float*)(smem + 12544);  // 16
        float* b2s = (float*)(smem + 12608);  // 2
        float* bs2 = (float*)(smem + 12616);  // 32
        w1s[t] = a.fcW1[t];
        w1s[t + 256] = a.fcW1[t + 256];
        if (t < 32) { w2s[t] = a.fcW2[t]; bs2[t] = a.b2v[t]; }
        if (t < 16) b1s[t] = a.fcb1[t];
        if (t < 2) b2s[t] = a.fcb2[t];
        __syncthreads();

        int li = t >> 3, fq = t & 7;
        const char* hb = (const char*)a.h2;
        for (int node0 = blockIdx.x * AGG_NODES; node0 < a.n;
             node0 += nB * AGG_NODES) {
            int i = node0 + li;
            bool live = (i < a.n);
            int e0 = a.offs[node0];
            int eEnd = (node0 + AGG_NODES < a.n) ? a.offs[node0 + AGG_NODES] : a.E;
            int myOff = 0, myCnt = 0;
            float4 acc = {0.f, 0.f, 0.f, 0.f};
            if (live) {
                myOff = a.offs[i];
                myCnt = ((i + 1 < a.n) ? a.offs[i + 1] : a.E) - myOff;
                half4 sv = *(const half4*)(hb + ((size_t)i << 6) + (fq << 3));
                acc.x = (float)sv.x; acc.y = (float)sv.y;
                acc.z = (float)sv.z; acc.w = (float)sv.w;
            }
            for (int cs = e0; cs < eEnd; cs += AGG_STAGE) {
                int ce = min(cs + AGG_STAGE, eEnd);
                for (int k = cs + t; k < ce; k += 256) sidx[k - cs] = a.srcs[k] << 6;
                __syncthreads();
                int ps = max(myOff, cs), pe = min(myOff + myCnt, ce);
                int p = ps;
                for (; p + 8 <= pe; p += 8) {
                    int o[8];
#pragma unroll
                    for (int u = 0; u < 8; ++u) o[u] = sidx[p + u - cs];
                    half4 v[8];
#pragma unroll
                    for (int u = 0; u < 8; ++u)
                        v[u] = *(const half4*)(hb + o[u] + (fq << 3));
#pragma unroll
                    for (int u = 0; u < 8; ++u) {
                        acc.x += (float)v[u].x; acc.y += (float)v[u].y;
                        acc.z += (float)v[u].z; acc.w += (float)v[u].w;
                    }
                }
                for (; p < pe; ++p) {
                    half4 v = *(const half4*)(hb + sidx[p - cs] + (fq << 3));
                    acc.x += (float)v.x; acc.y += (float)v.y;
                    acc.z += (float)v.z; acc.w += (float)v.w;
                }
                __syncthreads();
            }
            if (live) {
                float di = a.dinv[i];
                int f0 = fq << 2;
                sm[li * 33 + f0 + 0] = fmaxf(di * acc.x + bs2[f0 + 0], 0.f);
                sm[li * 33 + f0 + 1] = fmaxf(di * acc.y + bs2[f0 + 1], 0.f);
                sm[li * 33 + f0 + 2] = fmaxf(di * acc.z + bs2[f0 + 2], 0.f);
                sm[li * 33 + f0 + 3] = fmaxf(di * acc.w + bs2[f0 + 3], 0.f);
            }
            __syncthreads();
#pragma unroll
            for (int r = 0; r < 2; ++r) {
                int idx = r * 256 + t;
                int lj = idx >> 4, j = idx & 15;
                if (node0 + lj < a.n) {
                    float av = b1s[j];
#pragma unroll
                    for (int k = 0; k < 32; ++k)
                        av += sm[lj * 33 + k] * w1s[k * 16 + j];
                    x3s[lj * 16 + j] = fmaxf(av, 0.f);
                }
            }
            __syncthreads();
            if (t < 64) {
                int lj = t >> 1, o = t & 1;
                if (node0 + lj < a.n) {
                    float av = b2s[o];
#pragma unroll
                    for (int j = 0; j < 16; ++j)
                        av += x3s[lj * 16 + j] * w2s[j * 2 + o];
                    a.out[(size_t)(node0 + lj) * 2 + o] = av;
                }
            }
            __syncthreads();
        }
    }
}

// ======================= fallback path (r26, proven) =======================

__global__ __launch_bounds__(256) void histA(const int* __restrict__ dst,
                                             int* __restrict__ histG, int E) {
    __shared__ int h[MAXB];
    int t = threadIdx.x;
    h[t] = 0;
    h[t + 256] = 0;
    __syncthreads();
    int base = blockIdx.x * MS_TILE;
    int cnt = min(MS_TILE, E - base);
    for (int k = t; k < cnt; k += 256) atomicAdd(&h[dst[base + k] >> 8], 1);
    __syncthreads();
    histG[blockIdx.x * MAXB + t] = h[t];
    histG[blockIdx.x * MAXB + 256 + t] = h[t + 256];
}

__global__ __launch_bounds__(512) void scanTilesT(const int* __restrict__ histG,
                                                  int* __restrict__ offsG,
                                                  int* __restrict__ bucketTotal,
                                                  int nTiles) {
    __shared__ int lds[8][66];
    int t = threadIdx.x;
    int lane = t & 63, w = t >> 6;
    int rr = t >> 3, bb = t & 7;
    int B0 = blockIdx.x * 8;
    int carry = 0;
    for (int c0 = 0; c0 < nTiles; c0 += 64) {
        int rows = min(64, nTiles - c0);
        int v = 0;
        if (rr < rows) v = histG[(size_t)(c0 + rr) * MAXB + B0 + bb];
        lds[bb][rr] = v;
        __syncthreads();
        int x = lds[w][lane];
        int incl = x;
#pragma unroll
        for (int d = 1; d < 64; d <<= 1) {
            int up = __shfl_up(incl, d, 64);
            if (lane >= d) incl += up;
        }
        int total = __shfl(incl, 63, 64);
        lds[w][lane] = incl - x + carry;
        carry += total;
        __syncthreads();
        if (rr < rows) offsG[(size_t)(c0 + rr) * MAXB + B0 + bb] = lds[bb][rr];
        __syncthreads();
    }
    if (lane == 0) bucketTotal[B0 + w] = carry;
}

__global__ __launch_bounds__(256) void multisplit2(
    const int* __restrict__ src, const int* __restrict__ dst,
    const int* __restrict__ histG, const int* __restrict__ offsG,
    const int* __restrict__ btot, int* __restrict__ gbaseOut,
    unsigned* __restrict__ binned, int E) {
    __shared__ unsigned stage[MS_TILE];
    __shared__ unsigned short sb[MS_TILE];
    __shared__ int hoff[MAXB + 1];
    __shared__ int hcur[MAXB];
    __shared__ int gb[MAXB];
    __shared__ int wsum[4];
    int t = threadIdx.x;
    int lane = t & 63, w = t >> 6;
    int tile = blockIdx.x;
    int base = tile * MS_TILE;
    int cnt = min(MS_TILE, E - base);

    int b0 = btot[2 * t], b1v = btot[2 * t + 1];
    int s2 = b0 + b1v;
    int tot2;
    int incl2 = scan256_incl(s2, lane, w, wsum, &tot2);
    int ex2 = incl2 - s2;
    gb[2 * t] = ex2 + offsG[tile * MAXB + 2 * t];
    gb[2 * t + 1] = ex2 + b0 + offsG[tile * MAXB + 2 * t + 1];
    if (tile == 0) {
        gbaseOut[2 * t] = ex2;
        gbaseOut[2 * t + 1] = ex2 + b0;
        if (t == 255) gbaseOut[MAXB] = E;
    }
    __syncthreads();

    int a0 = histG[tile * MAXB + 2 * t];
    int a1 = histG[tile * MAXB + 2 * t + 1];
    int s = a0 + a1;
    int tot;
    int incl = scan256_incl(s, lane, w, wsum, &tot);
    int ex = incl - s;
    hoff[2 * t] = ex;
    hoff[2 * t + 1] = ex + a0;
    hcur[2 * t] = ex;
    hcur[2 * t + 1] = ex + a0;
    if (t == 255) hoff[MAXB] = cnt;
    __syncthreads();
    for (int k = t; k < cnt; k += 256) {
        int d = dst[base + k];
        int b = d >> 8;
        int p = atomicAdd(&hcur[b], 1);
        stage[p] = ((unsigned)src[base + k] << 8) | (unsigned)(d & 255);
        sb[p] = (unsigned short)b;
    }
    __syncthreads();
    for (int k = t; k < cnt; k += 256) {
        int b = sb[k];
        binned[gb[b] + (k - hoff[b])] = stage[k];
    }
}

__global__ __launch_bounds__(PF_T) void place_fine2(
    const unsigned* __restrict__ binned, const int* __restrict__ gbase,
    const float* __restrict__ x, int* __restrict__ offs,
    float* __restrict__ dinv, _Float16* __restrict__ y, int* __restrict__ srcs,
    int n) {
    __shared__ int cnt[256];
    __shared__ int baseL[256];
    __shared__ int wsum[8];
    __shared__ unsigned ovW[PF_OV];
    __shared__ int ovR[PF_OV];
    __shared__ int ovN;
    int t = threadIdx.x, b = blockIdx.x;
    int lane = t & 63, w = t >> 6;
    int node0 = b << 8;
    int nn = min(256, n - node0);
    int e0 = gbase[b], e1 = gbase[b + 1];
    if (t < 256) cnt[t] = 0;
    if (t == 0) ovN = 0;
    __syncthreads();

    unsigned wdv[PF_EPT];
    int rk[PF_EPT];
    int nc = 0;
#pragma unroll
    for (int u = 0; u < PF_EPT; ++u) {
        int k = e0 + t + u * PF_T;
        if (k < e1) {
            unsigned wd = binned[k];
            wdv[u] = wd;
            rk[u] = atomicAdd(&cnt[wd & 255u], 1);
            nc = u + 1;
        }
    }
    for (int k = e0 + t + PF_EPT * PF_T; k < e1; k += PF_T) {
        unsigned wd = binned[k];
        int r = atomicAdd(&cnt[wd & 255u], 1);
        int j = atomicAdd(&ovN, 1);
        if (j < PF_OV) { ovW[j] = wd; ovR[j] = r; }
    }
    __syncthreads();

    int c = (t < 256) ? cnt[t] : 0;
    int incl = c;
#pragma unroll
    for (int d = 1; d < 64; d <<= 1) {
        int up = __shfl_up(incl, d, 64);
        if (lane >= d) incl += up;
    }
    if (lane == 63) wsum[w] = incl;
    __syncthreads();
    int add = 0;
    if (w > 0) add += wsum[0];
    if (w > 1) add += wsum[1];
    if (w > 2) add += wsum[2];
    incl += add;
    if (t < 256) {
        int myoff = e0 + incl - c;
        baseL[t] = myoff;
        if (t < nn) {
            int node = node0 + t;
            offs[node] = myoff;
            float di = 1.0f / sqrtf((float)(c + 1));
            dinv[node] = di;
            const float* xr = x + (size_t)node * 5;
            half8 hv;
            hv[0] = (_Float16)(xr[0] * di);
            hv[1] = (_Float16)(xr[1] * di);
            hv[2] = (_Float16)(xr[2] * di);
            hv[3] = (_Float16)(xr[3] * di);
            hv[4] = (_Float16)(xr[4] * di);
            hv[5] = (_Float16)0.f;
            hv[6] = (_Float16)0.f;
            hv[7] = (_Float16)0.f;
            *(half8*)(y + (size_t)node * 8) = hv;
        }
    }
    __syncthreads();

#pragma unroll
    for (int u = 0; u < PF_EPT; ++u) {
        if (u < nc) {
            unsigned wd = wdv[u];
            srcs[baseL[wd & 255u] + rk[u]] = (int)(wd >> 8);
        }
    }
    int no = ovN;
    for (int j = t; j < no; j += PF_T) {
        unsigned wd = ovW[j];
        srcs[baseL[wd & 255u] + ovR[j]] = (int)(wd >> 8);
    }
}

__global__ __launch_bounds__(256) void agg1_t12(
    const _Float16* __restrict__ y, const int* __restrict__ srcs,
    const int* __restrict__ offs, const float* __restrict__ dinv,
    const float* __restrict__ W1, const float* __restrict__ b1,
    const float* __restrict__ W2, _Float16* __restrict__ h2, int n, int E) {
    __shared__ float w1s[320];
    __shared__ float b1s[64];
    __shared__ float w2s[64 * 32];
    __shared__ float o1[32 * 64];
    __shared__ float zs[32 * 6];
    int t = threadIdx.x;
    w1s[t] = W1[t];
    if (t < 64) {
        w1s[t + 256] = W1[t + 256];
        b1s[t] = b1[t];
    }
#pragma unroll
    for (int r = 0; r < 8; ++r) w2s[r * 256 + t] = W2[r * 256 + t];

    int node0 = blockIdx.x * 32;
    int li = t >> 3, e = t & 7;
    int i = node0 + li;
    const half8* yv = (const half8*)y;
    float a0 = 0.f, a1 = 0.f, a2 = 0.f, a3 = 0.f, a4 = 0.f;
    if (i < n) {
        int off = offs[i];
        int cnt = ((i + 1 < n) ? offs[i + 1] : E) - off;
        if (e == 0) {
            half8 v = yv[i];
            a0 = (float)v[0]; a1 = (float)v[1]; a2 = (float)v[2];
            a3 = (float)v[3]; a4 = (float)v[4];
        }
        for (int p = e; p < cnt; p += 8) {
            half8 v = yv[srcs[off + p]];
            a0 += (float)v[0]; a1 += (float)v[1]; a2 += (float)v[2];
            a3 += (float)v[3]; a4 += (float)v[4];
        }
    }
#pragma unroll
    for (int m = 4; m >= 1; m >>= 1) {
        a0 += __shfl_xor(a0, m, 64);
        a1 += __shfl_xor(a1, m, 64);
        a2 += __shfl_xor(a2, m, 64);
        a3 += __shfl_xor(a3, m, 64);
        a4 += __shfl_xor(a4, m, 64);
    }
    if (i < n && e == 0) {
        float di = dinv[i];
        zs[li * 6 + 0] = a0 * di;
        zs[li * 6 + 1] = a1 * di;
        zs[li * 6 + 2] = a2 * di;
        zs[li * 6 + 3] = a3 * di;
        zs[li * 6 + 4] = a4 * di;
        zs[li * 6 + 5] = di;
    }
    __syncthreads();
#pragma unroll
    for (int r = 0; r < 8; ++r) {
        int idx = r * 256 + t;
        int lj = idx >> 6, f = idx & 63;
        if (node0 + lj < n) {
            const float* zr = zs + lj * 6;
            float acc = b1s[f];
#pragma unroll
            for (int k = 0; k < 5; ++k) acc += zr[k] * w1s[k * 64 + f];
            o1[lj * 64 + f] = fmaxf(acc, 0.0f);
        }
    }
    __syncthreads();
#pragma unroll
    for (int r = 0; r < 4; ++r) {
        int idx = r * 256 + t;
        int lj = idx >> 5, g = idx & 31;
        int i2 = node0 + lj;
        if (i2 < n) {
            float acc = 0.f;
#pragma unroll
            for (int k = 0; k < 64; ++k) acc += o1[lj * 64 + k] * w2s[k * 32 + g];
            h2[(size_t)i2 * 32 + g] = (_Float16)(acc * zs[lj * 6 + 5]);
        }
    }
}

__global__ __launch_bounds__(256) void agg2_fc(
    const _Float16* __restrict__ h, const int* __restrict__ srcs,
    const int* __restrict__ offs, const float* __restrict__ dinv,
    const float* __restrict__ b2, const float* __restrict__ fcW1,
    const float* __restrict__ fcb1, const float* __restrict__ fcW2,
    const float* __restrict__ fcb2, float* __restrict__ out, int n, int E) {
    __shared__ int sidx[AGG_STAGE];
    __shared__ float sm[AGG_NODES * 33];
    __shared__ float x3s[AGG_NODES * 16];
    __shared__ float w1s[512];
    __shared__ float w2s[32];
    __shared__ float b1s[16];
    __shared__ float b2s[2];
    __shared__ float bs2[32];
    int t = threadIdx.x;
    w1s[t] = fcW1[t];
    w1s[t + 256] = fcW1[t + 256];
    if (t < 32) { w2s[t] = fcW2[t]; bs2[t] = b2[t]; }
    if (t < 16) b1s[t] = fcb1[t];
    if (t < 2) b2s[t] = fcb2[t];

    int node0 = blockIdx.x * AGG_NODES;
    int li = t >> 3, fq = t & 7;
    int i = node0 + li;
    bool live = (i < n);
    const char* hb = (const char*)h;

    int e0 = offs[node0];
    int eEnd = (node0 + AGG_NODES < n) ? offs[node0 + AGG_NODES] : E;
    int myOff = 0, myCnt = 0;
    float4 acc = {0.f, 0.f, 0.f, 0.f};
    if (live) {
        myOff = offs[i];
        myCnt = ((i + 1 < n) ? offs[i + 1] : E) - myOff;
        half4 sv = *(const half4*)(hb + ((size_t)i << 6) + (fq << 3));
        acc.x = (float)sv.x; acc.y = (float)sv.y;
        acc.z = (float)sv.z; acc.w = (float)sv.w;
    }

    for (int cs = e0; cs < eEnd; cs += AGG_STAGE) {
        int ce = min(cs + AGG_STAGE, eEnd);
        for (int k = cs + t; k < ce; k += 256) sidx[k - cs] = srcs[k] << 6;
        __syncthreads();
        int ps = max(myOff, cs), pe = min(myOff + myCnt, ce);
        int p = ps;
        for (; p + 8 <= pe; p += 8) {
            int o[8];
#pragma unroll
            for (int u = 0; u < 8; ++u) o[u] = sidx[p + u - cs];
            half4 v[8];
#pragma unroll
            for (int u = 0; u < 8; ++u)
                v[u] = *(const half4*)(hb + o[u] + (fq << 3));
#pragma unroll
            for (int u = 0; u < 8; ++u) {
                acc.x += (float)v[u].x; acc.y += (float)v[u].y;
                acc.z += (float)v[u].z; acc.w += (float)v[u].w;
            }
        }
        for (; p < pe; ++p) {
            half4 v = *(const half4*)(hb + sidx[p - cs] + (fq << 3));
            acc.x += (float)v.x; acc.y += (float)v.y;
            acc.z += (float)v.z; acc.w += (float)v.w;
        }
        __syncthreads();
    }

    if (live) {
        float di = dinv[i];
        int f0 = fq << 2;
        sm[li * 33 + f0 + 0] = fmaxf(di * acc.x + bs2[f0 + 0], 0.f);
        sm[li * 33 + f0 + 1] = fmaxf(di * acc.y + bs2[f0 + 1], 0.f);
        sm[li * 33 + f0 + 2] = fmaxf(di * acc.z + bs2[f0 + 2], 0.f);
        sm[li * 33 + f0 + 3] = fmaxf(di * acc.w + bs2[f0 + 3], 0.f);
    }
    __syncthreads();
#pragma unroll
    for (int r = 0; r < 2; ++r) {
        int idx = r * 256 + t;
        int lj = idx >> 4, j = idx & 15;
        if (node0 + lj < n) {
            float a = b1s[j];
#pragma unroll
            for (int k = 0; k < 32; ++k) a += sm[lj * 33 + k] * w1s[k * 16 + j];
            x3s[lj * 16 + j] = fmaxf(a, 0.f);
        }
    }
    __syncthreads();
    if (t < 64) {
        int lj = t >> 1, o = t & 1;
        if (node0 + lj < n) {
            float a = b2s[o];
#pragma unroll
            for (int j = 0; j < 16; ++j) a += x3s[lj * 16 + j] * w2s[j * 2 + o];
            out[(size_t)(node0 + lj) * 2 + o] = a;
        }
    }
}

extern "C" void kernel_launch(void* const* d_in, const int* in_sizes, int n_in,
                              void* d_out, int out_size, void* d_ws, size_t ws_size,
                              hipStream_t stream) {
    const float* edge_attr = (const float*)d_in[0];
    const int* edge_index  = (const int*)d_in[1];
    const float* W1   = (const float*)d_in[2];
    const float* b1   = (const float*)d_in[3];
    const float* W2   = (const float*)d_in[4];
    const float* b2   = (const float*)d_in[5];
    const float* fcW1 = (const float*)d_in[6];
    const float* fcb1 = (const float*)d_in[7];
    const float* fcW2 = (const float*)d_in[8];
    const float* fcb2 = (const float*)d_in[9];
    float* out = (float*)d_out;

    int n = in_sizes[0] / 5;
    int E = in_sizes[1] / 2;
    int NBkt = (n + 255) >> 8;
    int nTiles = (E + MS_TILE - 1) / MS_TILE;
    const int* src = edge_index;
    const int* dst = edge_index + E;

    char* ws = (char*)d_ws;
    auto alloc = [&](size_t bytes) {
        char* p = ws;
        ws += (bytes + 255) & ~(size_t)255;
        return p;
    };
    int*      offs   = (int*)alloc((size_t)n * 4);
    float*    dinv   = (float*)alloc((size_t)n * 4);
    int*      histG  = (int*)alloc((size_t)nTiles * MAXB * 4);
    int*      offsG  = (int*)alloc((size_t)nTiles * MAXB * 4);
    int*      btot   = (int*)alloc((size_t)MAXB * 4);
    int*      gbase  = (int*)alloc((size_t)(MAXB + 1) * 4);
    int*      srcs   = (int*)alloc((size_t)E * 4);
    unsigned* binned = (unsigned*)alloc((size_t)E * 4);
    _Float16* y      = (_Float16*)alloc((size_t)n * 8 * 2);
    _Float16* h2     = (_Float16*)alloc((size_t)n * 32 * 2);

    // one-time cooperative capability + grid sizing (host-side only; safe
    // under graph capture)
    static int g_grid = -1;
    if (g_grid < 0) {
        g_grid = 0;
        hipDeviceProp_t prop;
        if (hipGetDeviceProperties(&prop, 0) == hipSuccess &&
            prop.cooperativeLaunch) {
            int bpc = 0;
            if (hipOccupancyMaxActiveBlocksPerMultiprocessor(
                    &bpc, (const void*)mega, 256, (size_t)SMEM_BYTES) ==
                    hipSuccess && bpc > 0) {
                long gg = (long)bpc * prop.multiProcessorCount;
                if (gg > 2048) gg = 2048;
                g_grid = (int)gg;
            }
        }
    }

    bool launched = false;
    if (g_grid > 0) {
        MegaArgs ma;
        ma.src = src; ma.dst = dst; ma.x = edge_attr;
        ma.W1 = W1; ma.b1 = b1; ma.W2 = W2; ma.b2v = b2;
        ma.fcW1 = fcW1; ma.fcb1 = fcb1; ma.fcW2 = fcW2; ma.fcb2 = fcb2;
        ma.out = out;
        ma.histG = histG; ma.offsG = offsG; ma.btot = btot; ma.gbase = gbase;
        ma.offs = offs; ma.dinv = dinv; ma.y = y; ma.srcs = srcs;
        ma.binned = binned; ma.h2 = h2;
        ma.n = n; ma.E = E; ma.nTiles = nTiles;
        void* args[] = {&ma};
        if (hipLaunchCooperativeKernel((const void*)mega, dim3(g_grid),
                                       dim3(256), args,
                                       (unsigned)SMEM_BYTES, stream) ==
            hipSuccess) {
            launched = true;
        } else {
            g_grid = 0;  // disable for subsequent calls
        }
    }

    if (!launched) {  // proven 6-kernel fallback (r26)
        histA<<<nTiles, 256, 0, stream>>>(dst, histG, E);
        scanTilesT<<<MAXB / 8, 512, 0, stream>>>(histG, offsG, btot, nTiles);
        multisplit2<<<nTiles, 256, 0, stream>>>(src, dst, histG, offsG, btot,
                                                gbase, binned, E);
        place_fine2<<<NBkt, PF_T, 0, stream>>>(binned, gbase, edge_attr, offs,
                                               dinv, y, srcs, n);
        agg1_t12<<<(n + 31) / 32, 256, 0, stream>>>(y, srcs, offs, dinv, W1, b1,
                                                    W2, h2, n, E);
        agg2_fc<<<(n + AGG_NODES - 1) / AGG_NODES, 256, 0, stream>>>(
            h2, srcs, offs, dinv, b2, fcW1, fcb1, fcW2, fcb2, out, n, E);
    }
}

// Round 5
// 245.551 us; speedup vs baseline: 4.0063x; 4.0063x over previous
//
#include <hip/hip_runtime.h>

// ---------------------------------------------------------------------------
// GCN pipeline, round 29 (= r28 resubmission, hardened after container
// failure):
//   zero_deg -> histA_deg (tile hist + per-node deg atomics) ->
//   scanY (scanTilesT blocks || y/dinv blocks) -> multisplit2 (unchanged) ->
//   aggB1 (bucket-local LDS CSR rebuild + y-gather + W1/relu/W2 -> h2) ->
//   aggB2 (bucket-local LDS CSR rebuild + h2-gather + FC head -> out).
// Hardening vs r28: (1) hipMemsetAsync replaced by zero_deg kernel (removes
// the only new host-API-under-capture variable); (2) overflow-spill scatter
// into srcsL now bounds-guarded (was unguarded LDS OOB for >5120-edge
// buckets -- impossible for this input, but free to guard); (3) no other
// changes, so the r28 theory (kill the 20MB global CSR round-trip) is
// finally measured.
// ---------------------------------------------------------------------------

#define MS_TILE 2048
#define MAXB 512  // padded coarse-bucket count (NBkt = ceil(n/256) <= 512)
#define AB_T 512   // agg block threads
#define AB_EPT 10  // cached edges/thread (cap 5120/bucket; mean 4092, sd 64)
#define AB_CAP (AB_T * AB_EPT)
#define AB_OV 1024 // LDS spill for the (never-expected) overflow

typedef __attribute__((ext_vector_type(4))) _Float16 half4;
typedef __attribute__((ext_vector_type(8))) _Float16 half8;
typedef __attribute__((ext_vector_type(4))) int int4v;

// Inclusive shfl scan across 4 waves; cross-wave combine via wsum[4].
__device__ inline int scan256_incl(int v, int lane, int w, int* wsum,
                                   int* total) {
    int incl = v;
#pragma unroll
    for (int d = 1; d < 64; d <<= 1) {
        int up = __shfl_up(incl, d, 64);
        if (lane >= d) incl += up;
    }
    if (lane == 63) wsum[w] = incl;
    __syncthreads();
    int add = 0;
    if (w > 0) add += wsum[0];
    if (w > 1) add += wsum[1];
    if (w > 2) add += wsum[2];
    *total = wsum[0] + wsum[1] + wsum[2] + wsum[3];
    return incl + add;
}

// 400KB of zeros, coalesced int4 stores (replaces hipMemsetAsync).
__global__ __launch_bounds__(256) void zero_deg(int* __restrict__ deg, int n4) {
    int i = blockIdx.x * 256 + threadIdx.x;
    if (i < n4) ((int4v*)deg)[i] = int4v{0, 0, 0, 0};
}

// per-tile LDS histogram of dst>>8 -> histG rows; PLUS per-node degree via
// fire-and-forget global atomics (1.6M adds over 100K addrs, ~16/addr).
__global__ __launch_bounds__(256) void histA_deg(const int* __restrict__ dst,
                                                 int* __restrict__ histG,
                                                 int* __restrict__ deg, int E) {
    __shared__ int h[MAXB];
    int t = threadIdx.x;
    h[t] = 0;
    h[t + 256] = 0;
    __syncthreads();
    int base = blockIdx.x * MS_TILE;
    int cnt = min(MS_TILE, E - base);
    for (int k = t; k < cnt; k += 256) {
        int d = dst[base + k];
        atomicAdd(&h[d >> 8], 1);
        atomicAdd(&deg[d], 1);
    }
    __syncthreads();
    histG[blockIdx.x * MAXB + t] = h[t];
    histG[blockIdx.x * MAXB + 256 + t] = h[t + 256];
}

// Fused: blocks [0,64) = transposed tile-offset scan (8 buckets each,
// r26-proven); blocks [64,..) = dinv/y compute from deg (grid-stride).
__global__ __launch_bounds__(512) void scanY(const int* __restrict__ histG,
                                             int* __restrict__ offsG,
                                             int* __restrict__ bucketTotal,
                                             const int* __restrict__ deg,
                                             const float* __restrict__ x,
                                             float* __restrict__ dinv,
                                             _Float16* __restrict__ y,
                                             int nTiles, int n) {
    __shared__ int lds[8][66];
    int t = threadIdx.x;
    if (blockIdx.x < 64) {
        int lane = t & 63, w = t >> 6;
        int rr = t >> 3, bb = t & 7;
        int B0 = blockIdx.x * 8;
        int carry = 0;
        for (int c0 = 0; c0 < nTiles; c0 += 64) {
            int rows = min(64, nTiles - c0);
            int v = 0;
            if (rr < rows) v = histG[(size_t)(c0 + rr) * MAXB + B0 + bb];
            lds[bb][rr] = v;
            __syncthreads();
            int x0 = lds[w][lane];
            int incl = x0;
#pragma unroll
            for (int d = 1; d < 64; d <<= 1) {
                int up = __shfl_up(incl, d, 64);
                if (lane >= d) incl += up;
            }
            int total = __shfl(incl, 63, 64);
            lds[w][lane] = incl - x0 + carry;
            carry += total;
            __syncthreads();
            if (rr < rows) offsG[(size_t)(c0 + rr) * MAXB + B0 + bb] = lds[bb][rr];
            __syncthreads();
        }
        if (lane == 0) bucketTotal[B0 + w] = carry;
    } else {
        int base = (blockIdx.x - 64) * 512;
        int stride = (gridDim.x - 64) * 512;
        for (int i = base + t; i < n; i += stride) {
            float di = 1.0f / sqrtf((float)(deg[i] + 1));  // +1 self loop
            dinv[i] = di;
            const float* xr = x + (size_t)i * 5;
            half8 hv;
            hv[0] = (_Float16)(xr[0] * di);
            hv[1] = (_Float16)(xr[1] * di);
            hv[2] = (_Float16)(xr[2] * di);
            hv[3] = (_Float16)(xr[3] * di);
            hv[4] = (_Float16)(xr[4] * di);
            hv[5] = (_Float16)0.f;
            hv[6] = (_Float16)0.f;
            hv[7] = (_Float16)0.f;
            *(half8*)(y + (size_t)i * 8) = hv;
        }
    }
}

// Deterministic tile counting-sort. Payload: (src<<8)|(dst&255). Unchanged.
__global__ __launch_bounds__(256) void multisplit2(
    const int* __restrict__ src, const int* __restrict__ dst,
    const int* __restrict__ histG, const int* __restrict__ offsG,
    const int* __restrict__ btot, int* __restrict__ gbaseOut,
    unsigned* __restrict__ binned, int E) {
    __shared__ unsigned stage[MS_TILE];
    __shared__ unsigned short sb[MS_TILE];
    __shared__ int hoff[MAXB + 1];
    __shared__ int hcur[MAXB];
    __shared__ int gb[MAXB];
    __shared__ int wsum[4];
    int t = threadIdx.x;
    int lane = t & 63, w = t >> 6;
    int tile = blockIdx.x;
    int base = tile * MS_TILE;
    int cnt = min(MS_TILE, E - base);

    int b0 = btot[2 * t], b1v = btot[2 * t + 1];
    int s2 = b0 + b1v;
    int tot2;
    int incl2 = scan256_incl(s2, lane, w, wsum, &tot2);
    int ex2 = incl2 - s2;
    gb[2 * t] = ex2 + offsG[tile * MAXB + 2 * t];
    gb[2 * t + 1] = ex2 + b0 + offsG[tile * MAXB + 2 * t + 1];
    if (tile == 0) {
        gbaseOut[2 * t] = ex2;
        gbaseOut[2 * t + 1] = ex2 + b0;
        if (t == 255) gbaseOut[MAXB] = E;
    }
    __syncthreads();

    int a0 = histG[tile * MAXB + 2 * t];
    int a1 = histG[tile * MAXB + 2 * t + 1];
    int s = a0 + a1;
    int tot;
    int incl = scan256_incl(s, lane, w, wsum, &tot);
    int ex = incl - s;
    hoff[2 * t] = ex;
    hoff[2 * t + 1] = ex + a0;
    hcur[2 * t] = ex;
    hcur[2 * t + 1] = ex + a0;
    if (t == 255) hoff[MAXB] = cnt;
    __syncthreads();
    for (int k = t; k < cnt; k += 256) {
        int d = dst[base + k];
        int b = d >> 8;
        int p = atomicAdd(&hcur[b], 1);
        stage[p] = ((unsigned)src[base + k] << 8) | (unsigned)(d & 255);
        sb[p] = (unsigned short)b;
    }
    __syncthreads();
    for (int k = t; k < cnt; k += 256) {
        int b = sb[k];
        binned[gb[b] + (k - hoff[b])] = stage[k];
    }
}

// Layer-1: local CSR + y-gather (8 thr/node, half8) + W1/relu/W2 -> fp16 h2.
__global__ __launch_bounds__(AB_T) void aggB1(
    const unsigned* __restrict__ binned, const int* __restrict__ gbase,
    const _Float16* __restrict__ y, const float* __restrict__ dinv,
    const float* __restrict__ W1, const float* __restrict__ b1,
    const float* __restrict__ W2, _Float16* __restrict__ h2, int n, int E) {
    __shared__ int cntL[256];
    __shared__ int exL[256];
    __shared__ int wsum[8];
    __shared__ int srcsL[AB_CAP];
    __shared__ unsigned ovW[AB_OV];
    __shared__ int ovR[AB_OV];
    __shared__ int ovN;
    __shared__ float w1s[320];
    __shared__ float b1s[64];
    __shared__ float w2s[2048];
    __shared__ float o1[64 * 64];
    __shared__ float zs[64 * 6];
    int t = threadIdx.x, b = blockIdx.x;
    int lane = t & 63, w = t >> 6;
    int node0 = b << 8;
    int e0 = gbase[b], e1 = gbase[b + 1];

    if (t < 320) w1s[t] = W1[t];
    if (t < 64) b1s[t] = b1[t];
#pragma unroll
    for (int r = 0; r < 4; ++r) w2s[r * 512 + t] = W2[r * 512 + t];
    if (t < 256) cntL[t] = 0;
    if (t == 0) ovN = 0;
    __syncthreads();

    // phase A: load + rank (atomic ret = final intra-node rank)
    unsigned wdv[AB_EPT];
    int rk[AB_EPT];
    int nc = 0;
#pragma unroll
    for (int u = 0; u < AB_EPT; ++u) {
        int k = e0 + t + u * AB_T;
        if (k < e1) {
            unsigned wd = binned[k];
            wdv[u] = wd;
            rk[u] = atomicAdd(&cntL[wd & 255u], 1);
            nc = u + 1;
        }
    }
    for (int k = e0 + t + AB_EPT * AB_T; k < e1; k += AB_T) {
        unsigned wd = binned[k];
        int r = atomicAdd(&cntL[wd & 255u], 1);
        int j = atomicAdd(&ovN, 1);
        if (j < AB_OV) { ovW[j] = wd; ovR[j] = r; }
    }
    __syncthreads();
    int c = (t < 256) ? cntL[t] : 0;
    int incl = c;
#pragma unroll
    for (int d = 1; d < 64; d <<= 1) {
        int up = __shfl_up(incl, d, 64);
        if (lane >= d) incl += up;
    }
    if (lane == 63) wsum[w] = incl;
    __syncthreads();
    int add = 0;
    if (w > 0) add += wsum[0];
    if (w > 1) add += wsum[1];
    if (w > 2) add += wsum[2];
    incl += add;
    if (t < 256) exL[t] = incl - c;
    __syncthreads();
#pragma unroll
    for (int u = 0; u < AB_EPT; ++u) {
        if (u < nc) {
            unsigned wd = wdv[u];
            int pos = exL[wd & 255u] + rk[u];
            if (pos < AB_CAP) srcsL[pos] = (int)(wd >> 8);
        }
    }
    int no = min(ovN, AB_OV);
    for (int j = t; j < no; j += AB_T) {
        unsigned wd = ovW[j];
        int pos = exL[wd & 255u] + ovR[j];
        if (pos < AB_CAP) srcsL[pos] = (int)(wd >> 8);
    }
    __syncthreads();

    // phase B: gather + transforms, 4 groups of 64 nodes
    const half8* yv = (const half8*)y;
    int li = t >> 3, e = t & 7;
    for (int g = 0; g < 4; ++g) {
        int l = g * 64 + li;
        int i = node0 + l;
        float a0 = 0.f, a1 = 0.f, a2 = 0.f, a3 = 0.f, a4 = 0.f;
        if (i < n) {
            int myo = exL[l], myc = cntL[l];
            if (e == 0) {  // self-loop term once per node
                half8 v = yv[i];
                a0 = (float)v[0]; a1 = (float)v[1]; a2 = (float)v[2];
                a3 = (float)v[3]; a4 = (float)v[4];
            }
            for (int p = e; p < myc; p += 8) {
                half8 v = yv[srcsL[myo + p]];
                a0 += (float)v[0]; a1 += (float)v[1]; a2 += (float)v[2];
                a3 += (float)v[3]; a4 += (float)v[4];
            }
        }
#pragma unroll
        for (int m = 4; m >= 1; m >>= 1) {
            a0 += __shfl_xor(a0, m, 64);
            a1 += __shfl_xor(a1, m, 64);
            a2 += __shfl_xor(a2, m, 64);
            a3 += __shfl_xor(a3, m, 64);
            a4 += __shfl_xor(a4, m, 64);
        }
        if (i < n && e == 0) {
            float di = dinv[i];
            zs[li * 6 + 0] = a0 * di;
            zs[li * 6 + 1] = a1 * di;
            zs[li * 6 + 2] = a2 * di;
            zs[li * 6 + 3] = a3 * di;
            zs[li * 6 + 4] = a4 * di;
            zs[li * 6 + 5] = di;
        }
        __syncthreads();
#pragma unroll
        for (int r = 0; r < 8; ++r) {
            int idx = r * 512 + t;
            int lj = idx >> 6, f = idx & 63;
            if (node0 + g * 64 + lj < n) {
                const float* zr = zs + lj * 6;
                float acc = b1s[f];
#pragma unroll
                for (int k = 0; k < 5; ++k) acc += zr[k] * w1s[k * 64 + f];
                o1[lj * 64 + f] = fmaxf(acc, 0.0f);
            }
        }
        __syncthreads();
#pragma unroll
        for (int r = 0; r < 4; ++r) {
            int idx = r * 512 + t;
            int lj = idx >> 5, gg = idx & 31;
            int i2 = node0 + g * 64 + lj;
            if (i2 < n) {
                float acc = 0.f;
#pragma unroll
                for (int k = 0; k < 64; ++k)
                    acc += o1[lj * 64 + k] * w2s[k * 32 + gg];
                h2[(size_t)i2 * 32 + gg] = (_Float16)(acc * zs[lj * 6 + 5]);
            }
        }
        __syncthreads();
    }
}

// Layer-2: local CSR + h2-gather (8 thr/node, half4 slices) + FC head.
__global__ __launch_bounds__(AB_T) void aggB2(
    const unsigned* __restrict__ binned, const int* __restrict__ gbase,
    const _Float16* __restrict__ h, const float* __restrict__ dinv,
    const float* __restrict__ b2, const float* __restrict__ fcW1,
    const float* __restrict__ fcb1, const float* __restrict__ fcW2,
    const float* __restrict__ fcb2, float* __restrict__ out, int n, int E) {
    __shared__ int cntL[256];
    __shared__ int exL[256];
    __shared__ int wsum[8];
    __shared__ int srcsL[AB_CAP];
    __shared__ unsigned ovW[AB_OV];
    __shared__ int ovR[AB_OV];
    __shared__ int ovN;
    __shared__ float sm[64 * 33];
    __shared__ float x3s[64 * 16];
    __shared__ float w1s[512];
    __shared__ float w2sF[32];
    __shared__ float b1sF[16];
    __shared__ float b2sF[2];
    __shared__ float bs2[32];
    int t = threadIdx.x, b = blockIdx.x;
    int lane = t & 63, w = t >> 6;
    int node0 = b << 8;
    int e0 = gbase[b], e1 = gbase[b + 1];

    if (t < 512) w1s[t] = fcW1[t];
    if (t < 32) { w2sF[t] = fcW2[t]; bs2[t] = b2[t]; }
    if (t < 16) b1sF[t] = fcb1[t];
    if (t < 2) b2sF[t] = fcb2[t];
    if (t < 256) cntL[t] = 0;
    if (t == 0) ovN = 0;
    __syncthreads();

    // phase A: identical local CSR rebuild
    unsigned wdv[AB_EPT];
    int rk[AB_EPT];
    int nc = 0;
#pragma unroll
    for (int u = 0; u < AB_EPT; ++u) {
        int k = e0 + t + u * AB_T;
        if (k < e1) {
            unsigned wd = binned[k];
            wdv[u] = wd;
            rk[u] = atomicAdd(&cntL[wd & 255u], 1);
            nc = u + 1;
        }
    }
    for (int k = e0 + t + AB_EPT * AB_T; k < e1; k += AB_T) {
        unsigned wd = binned[k];
        int r = atomicAdd(&cntL[wd & 255u], 1);
        int j = atomicAdd(&ovN, 1);
        if (j < AB_OV) { ovW[j] = wd; ovR[j] = r; }
    }
    __syncthreads();
    int c = (t < 256) ? cntL[t] : 0;
    int incl = c;
#pragma unroll
    for (int d = 1; d < 64; d <<= 1) {
        int up = __shfl_up(incl, d, 64);
        if (lane >= d) incl += up;
    }
    if (lane == 63) wsum[w] = incl;
    __syncthreads();
    int add = 0;
    if (w > 0) add += wsum[0];
    if (w > 1) add += wsum[1];
    if (w > 2) add += wsum[2];
    incl += add;
    if (t < 256) exL[t] = incl - c;
    __syncthreads();
#pragma unroll
    for (int u = 0; u < AB_EPT; ++u) {
        if (u < nc) {
            unsigned wd = wdv[u];
            int pos = exL[wd & 255u] + rk[u];
            if (pos < AB_CAP) srcsL[pos] = (int)(wd >> 8);
        }
    }
    int no = min(ovN, AB_OV);
    for (int j = t; j < no; j += AB_T) {
        unsigned wd = ovW[j];
        int pos = exL[wd & 255u] + ovR[j];
        if (pos < AB_CAP) srcsL[pos] = (int)(wd >> 8);
    }
    __syncthreads();

    // phase B: h2 gather + FC head, 4 groups of 64 nodes
    int li = t >> 3, fq = t & 7;
    const char* hb = (const char*)h;
    for (int g = 0; g < 4; ++g) {
        int l = g * 64 + li;
        int i = node0 + l;
        bool live = (i < n);
        float4 acc = {0.f, 0.f, 0.f, 0.f};
        int myo = 0, myc = 0;
        if (live) {
            myo = exL[l];
            myc = cntL[l];
            half4 sv = *(const half4*)(hb + ((size_t)i << 6) + (fq << 3));
            acc.x = (float)sv.x; acc.y = (float)sv.y;
            acc.z = (float)sv.z; acc.w = (float)sv.w;
        }
        int p = 0;
        for (; p + 8 <= myc; p += 8) {
            int o[8];
#pragma unroll
            for (int u = 0; u < 8; ++u) o[u] = srcsL[myo + p + u] << 6;
            half4 v[8];
#pragma unroll
            for (int u = 0; u < 8; ++u)
                v[u] = *(const half4*)(hb + o[u] + (fq << 3));
#pragma unroll
            for (int u = 0; u < 8; ++u) {
                acc.x += (float)v[u].x; acc.y += (float)v[u].y;
                acc.z += (float)v[u].z; acc.w += (float)v[u].w;
            }
        }
        for (; p + 4 <= myc; p += 4) {
            int o0 = srcsL[myo + p] << 6, o1v = srcsL[myo + p + 1] << 6;
            int o2 = srcsL[myo + p + 2] << 6, o3 = srcsL[myo + p + 3] << 6;
            half4 v0 = *(const half4*)(hb + o0 + (fq << 3));
            half4 v1 = *(const half4*)(hb + o1v + (fq << 3));
            half4 v2 = *(const half4*)(hb + o2 + (fq << 3));
            half4 v3 = *(const half4*)(hb + o3 + (fq << 3));
            acc.x += (float)v0.x + (float)v1.x + (float)v2.x + (float)v3.x;
            acc.y += (float)v0.y + (float)v1.y + (float)v2.y + (float)v3.y;
            acc.z += (float)v0.z + (float)v1.z + (float)v2.z + (float)v3.z;
            acc.w += (float)v0.w + (float)v1.w + (float)v2.w + (float)v3.w;
        }
        for (; p < myc; ++p) {
            half4 v = *(const half4*)(hb + (srcsL[myo + p] << 6) + (fq << 3));
            acc.x += (float)v.x; acc.y += (float)v.y;
            acc.z += (float)v.z; acc.w += (float)v.w;
        }
        if (live) {
            float di = dinv[i];
            int f0 = fq << 2;
            sm[li * 33 + f0 + 0] = fmaxf(di * acc.x + bs2[f0 + 0], 0.f);
            sm[li * 33 + f0 + 1] = fmaxf(di * acc.y + bs2[f0 + 1], 0.f);
            sm[li * 33 + f0 + 2] = fmaxf(di * acc.z + bs2[f0 + 2], 0.f);
            sm[li * 33 + f0 + 3] = fmaxf(di * acc.w + bs2[f0 + 3], 0.f);
        }
        __syncthreads();
#pragma unroll
        for (int r = 0; r < 2; ++r) {
            int idx = r * 512 + t;
            int lj = idx >> 4, j = idx & 15;
            if (node0 + g * 64 + lj < n) {
                float a = b1sF[j];
#pragma unroll
                for (int k = 0; k < 32; ++k) a += sm[lj * 33 + k] * w1s[k * 16 + j];
                x3s[lj * 16 + j] = fmaxf(a, 0.f);
            }
        }
        __syncthreads();
        if (t < 128) {
            int lj = t >> 1, o = t & 1;
            if (node0 + g * 64 + lj < n) {
                float a = b2sF[o];
#pragma unroll
                for (int j = 0; j < 16; ++j)
                    a += x3s[lj * 16 + j] * w2sF[j * 2 + o];
                out[(size_t)(node0 + g * 64 + lj) * 2 + o] = a;
            }
        }
        __syncthreads();
    }
}

extern "C" void kernel_launch(void* const* d_in, const int* in_sizes, int n_in,
                              void* d_out, int out_size, void* d_ws, size_t ws_size,
                              hipStream_t stream) {
    const float* edge_attr = (const float*)d_in[0];
    const int* edge_index  = (const int*)d_in[1];
    const float* W1   = (const float*)d_in[2];
    const float* b1   = (const float*)d_in[3];
    const float* W2   = (const float*)d_in[4];
    const float* b2   = (const float*)d_in[5];
    const float* fcW1 = (const float*)d_in[6];
    const float* fcb1 = (const float*)d_in[7];
    const float* fcW2 = (const float*)d_in[8];
    const float* fcb2 = (const float*)d_in[9];
    float* out = (float*)d_out;

    int n = in_sizes[0] / 5;
    int E = in_sizes[1] / 2;
    int NBkt = (n + 255) >> 8;                 // 391 for n=100000 (<= MAXB)
    int nTiles = (E + MS_TILE - 1) / MS_TILE;  // 782
    const int* src = edge_index;
    const int* dst = edge_index + E;

    char* ws = (char*)d_ws;
    auto alloc = [&](size_t bytes) {
        char* p = ws;
        ws += (bytes + 255) & ~(size_t)255;
        return p;
    };
    int*      deg    = (int*)alloc((size_t)n * 4 + 16);
    float*    dinv   = (float*)alloc((size_t)n * 4);
    int*      histG  = (int*)alloc((size_t)nTiles * MAXB * 4);
    int*      offsG  = (int*)alloc((size_t)nTiles * MAXB * 4);
    int*      btot   = (int*)alloc((size_t)MAXB * 4);
    int*      gbase  = (int*)alloc((size_t)(MAXB + 1) * 4);
    unsigned* binned = (unsigned*)alloc((size_t)E * 4);
    _Float16* y      = (_Float16*)alloc((size_t)n * 8 * 2);
    _Float16* h2     = (_Float16*)alloc((size_t)n * 32 * 2);

    int n4 = (n + 3) >> 2;
    zero_deg<<<(n4 + 255) / 256, 256, 0, stream>>>(deg, n4);
    histA_deg<<<nTiles, 256, 0, stream>>>(dst, histG, deg, E);
    scanY<<<64 + 128, 512, 0, stream>>>(histG, offsG, btot, deg, edge_attr,
                                        dinv, y, nTiles, n);
    multisplit2<<<nTiles, 256, 0, stream>>>(src, dst, histG, offsG, btot, gbase,
                                            binned, E);
    aggB1<<<NBkt, AB_T, 0, stream>>>(binned, gbase, y, dinv, W1, b1, W2, h2, n,
                                     E);
    aggB2<<<NBkt, AB_T, 0, stream>>>(binned, gbase, h2, dinv, b2, fcW1, fcb1,
                                     fcW2, fcb2, out, n, E);
}

// Round 6
// 173.169 us; speedup vs baseline: 5.6809x; 1.4180x over previous
//
#include <hip/hip_runtime.h>

// ---------------------------------------------------------------------------
// GCN pipeline, round 30: r26 structure (global CSR, NO global atomics)
// with 4096-edge sort tiles (512-thread histA/multisplit2).
//   histA -> scanTilesT -> multisplit2 -> place_fine2 (single-pass) ->
//   agg1_t12 -> agg2_fc.
// r29 lessons (counter-backed): (1) global atomicAdd = 55us for 1.6M ops +
// 51MB write amplification -- dead on 8 XCDs; (2) the 20MB global CSR
// round-trip is ~free (local-CSR aggs cost the same) -- kernels sit on
// latency/fixed-cost floors, not BW. This round halves the per-tile fixed
// costs (scans, barriers, bookkeeping) in the three sort kernels by
// doubling the tile: 782 -> 391 tiles, 2048 -> 4096 edges @ 512 threads.
// If null again at ~177, the per-dispatch floor model is confirmed and the
// pipeline is at its practical plateau.
// ---------------------------------------------------------------------------

#define MS_TILE 4096
#define MS_T 512
#define MAXB 512  // coarse-bucket count (256 nodes each; NBkt=391 <= 512)
#define AGG_NODES 32
#define AGG_STAGE 1024
#define PF_T 512   // place_fine2 threads
#define PF_EPT 10  // cached edges/thread (cap 5120/bucket; mean 4096, sd 64)
#define PF_OV 1024 // LDS spill capacity for the (never-expected) overflow

typedef __attribute__((ext_vector_type(4))) _Float16 half4;
typedef __attribute__((ext_vector_type(8))) _Float16 half8;

// Inclusive shfl scan across 8 waves (512 threads); combine via wsum[8].
// Caller must ensure no pending reads of wsum from a previous call (insert
// __syncthreads() between consecutive calls).
__device__ inline int scan512_incl(int v, int lane, int w, int* wsum,
                                   int* total) {
    int incl = v;
#pragma unroll
    for (int d = 1; d < 64; d <<= 1) {
        int up = __shfl_up(incl, d, 64);
        if (lane >= d) incl += up;
    }
    if (lane == 63) wsum[w] = incl;
    __syncthreads();
    int add = 0;
#pragma unroll
    for (int ww = 0; ww < 8; ++ww)
        if (ww < w) add += wsum[ww];
    int tot = 0;
#pragma unroll
    for (int ww = 0; ww < 8; ++ww) tot += wsum[ww];
    *total = tot;
    return incl + add;
}

// per-tile LDS histogram of dst>>8 -> histG[tile*512 + b] (coalesced rows)
__global__ __launch_bounds__(MS_T) void histA(const int* __restrict__ dst,
                                              int* __restrict__ histG, int E) {
    __shared__ int h[MAXB];
    int t = threadIdx.x;
    h[t] = 0;
    __syncthreads();
    int base = blockIdx.x * MS_TILE;
    int cnt = min(MS_TILE, E - base);
    for (int k = t; k < cnt; k += MS_T) atomicAdd(&h[dst[base + k] >> 8], 1);
    __syncthreads();
    histG[blockIdx.x * MAXB + t] = h[t];
}

// Tiled transpose scan: block owns 8 buckets; per 64-tile chunk, load the
// 64x8 sub-panel of histG coalesced, transpose via LDS, shfl-scan each
// bucket in its own wave (register carry), write offsG back coalesced.
__global__ __launch_bounds__(512) void scanTilesT(const int* __restrict__ histG,
                                                  int* __restrict__ offsG,
                                                  int* __restrict__ bucketTotal,
                                                  int nTiles) {
    __shared__ int lds[8][66];
    int t = threadIdx.x;
    int lane = t & 63, w = t >> 6;  // wave w scans bucket B0 + w
    int rr = t >> 3, bb = t & 7;    // load/store mapping (row rr, bucket bb)
    int B0 = blockIdx.x * 8;
    int carry = 0;
    for (int c0 = 0; c0 < nTiles; c0 += 64) {
        int rows = min(64, nTiles - c0);
        int v = 0;
        if (rr < rows) v = histG[(size_t)(c0 + rr) * MAXB + B0 + bb];
        lds[bb][rr] = v;
        __syncthreads();
        int x = lds[w][lane];
        int incl = x;
#pragma unroll
        for (int d = 1; d < 64; d <<= 1) {
            int up = __shfl_up(incl, d, 64);
            if (lane >= d) incl += up;
        }
        int total = __shfl(incl, 63, 64);
        lds[w][lane] = incl - x + carry;  // exclusive prefix + running carry
        carry += total;
        __syncthreads();
        if (rr < rows) offsG[(size_t)(c0 + rr) * MAXB + B0 + bb] = lds[bb][rr];
        __syncthreads();
    }
    if (lane == 0) bucketTotal[B0 + w] = carry;
}

// Deterministic tile counting-sort, 4096-edge tiles @ 512 threads.
// Payload: (src<<8)|(dst&255).
__global__ __launch_bounds__(MS_T) void multisplit2(
    const int* __restrict__ src, const int* __restrict__ dst,
    const int* __restrict__ histG, const int* __restrict__ offsG,
    const int* __restrict__ btot, int* __restrict__ gbaseOut,
    unsigned* __restrict__ binned, int E) {
    __shared__ unsigned stage[MS_TILE];
    __shared__ unsigned short sb[MS_TILE];
    __shared__ int hoff[MAXB + 1];
    __shared__ int hcur[MAXB];
    __shared__ int gb[MAXB];
    __shared__ int wsum[8];
    int t = threadIdx.x;
    int lane = t & 63, w = t >> 6;
    int tile = blockIdx.x;
    int base = tile * MS_TILE;
    int cnt = min(MS_TILE, E - base);

    // bucket-base scan (tile-invariant; one bucket per thread)
    int s2 = btot[t];
    int tot2;
    int incl2 = scan512_incl(s2, lane, w, wsum, &tot2);
    int ex2 = incl2 - s2;
    gb[t] = ex2 + offsG[tile * MAXB + t];
    if (tile == 0) {
        gbaseOut[t] = ex2;
        if (t == MAXB - 1) gbaseOut[MAXB] = E;
    }
    __syncthreads();  // wsum reuse fence

    // tile-local hist scan (one bucket per thread)
    int a0 = histG[tile * MAXB + t];
    int tot;
    int incl = scan512_incl(a0, lane, w, wsum, &tot);
    int ex = incl - a0;
    hoff[t] = ex;
    hcur[t] = ex;
    if (t == MAXB - 1) hoff[MAXB] = cnt;
    __syncthreads();

    for (int k = t; k < cnt; k += MS_T) {
        int d = dst[base + k];
        int b = d >> 8;
        int p = atomicAdd(&hcur[b], 1);
        stage[p] = ((unsigned)src[base + k] << 8) | (unsigned)(d & 255);
        sb[p] = (unsigned short)b;
    }
    __syncthreads();
    for (int k = t; k < cnt; k += MS_T) {
        int b = sb[k];
        binned[gb[b] + (k - hoff[b])] = stage[k];
    }
}

// Per coarse bucket: SINGLE pass over binned (register-cached), first
// atomicAdd doubles as the final intra-node rank. Then shfl scan -> offs,
// dinv, y rows, and an atomic-free register scatter of srcs.
__global__ __launch_bounds__(PF_T) void place_fine2(
    const unsigned* __restrict__ binned, const int* __restrict__ gbase,
    const float* __restrict__ x, int* __restrict__ offs,
    float* __restrict__ dinv, _Float16* __restrict__ y, int* __restrict__ srcs,
    int n) {
    __shared__ int cnt[256];
    __shared__ int baseL[256];
    __shared__ int wsum[8];
    __shared__ unsigned ovW[PF_OV];
    __shared__ int ovR[PF_OV];
    __shared__ int ovN;
    int t = threadIdx.x, b = blockIdx.x;
    int lane = t & 63, w = t >> 6;
    int node0 = b << 8;
    int nn = min(256, n - node0);
    int e0 = gbase[b], e1 = gbase[b + 1];
    if (t < 256) cnt[t] = 0;
    if (t == 0) ovN = 0;
    __syncthreads();

    // pass 1: load + count; the atomic's return value IS the final rank.
    unsigned wdv[PF_EPT];
    int rk[PF_EPT];
    int nc = 0;
#pragma unroll
    for (int u = 0; u < PF_EPT; ++u) {
        int k = e0 + t + u * PF_T;
        if (k < e1) {
            unsigned wd = binned[k];
            wdv[u] = wd;
            rk[u] = atomicAdd(&cnt[wd & 255u], 1);
            nc = u + 1;
        }
    }
    // overflow tail (bucket > PF_EPT*PF_T edges -- never expected; LDS spill)
    for (int k = e0 + t + PF_EPT * PF_T; k < e1; k += PF_T) {
        unsigned wd = binned[k];
        int r = atomicAdd(&cnt[wd & 255u], 1);
        int j = atomicAdd(&ovN, 1);
        if (j < PF_OV) { ovW[j] = wd; ovR[j] = r; }
    }
    __syncthreads();

    // scan counts across the first 4 waves (waves 4..7 carry zeros).
    int c = (t < 256) ? cnt[t] : 0;
    int incl = c;
#pragma unroll
    for (int d = 1; d < 64; d <<= 1) {
        int up = __shfl_up(incl, d, 64);
        if (lane >= d) incl += up;
    }
    if (lane == 63) wsum[w] = incl;
    __syncthreads();
    int add = 0;
    if (w > 0) add += wsum[0];
    if (w > 1) add += wsum[1];
    if (w > 2) add += wsum[2];
    incl += add;
    if (t < 256) {
        int myoff = e0 + incl - c;
        baseL[t] = myoff;
        if (t < nn) {
            int node = node0 + t;
            offs[node] = myoff;
            float di = 1.0f / sqrtf((float)(c + 1));  // +1 self loop
            dinv[node] = di;
            const float* xr = x + (size_t)node * 5;
            half8 hv;
            hv[0] = (_Float16)(xr[0] * di);
            hv[1] = (_Float16)(xr[1] * di);
            hv[2] = (_Float16)(xr[2] * di);
            hv[3] = (_Float16)(xr[3] * di);
            hv[4] = (_Float16)(xr[4] * di);
            hv[5] = (_Float16)0.f;
            hv[6] = (_Float16)0.f;
            hv[7] = (_Float16)0.f;
            *(half8*)(y + (size_t)node * 8) = hv;
        }
    }
    __syncthreads();

    // pass 2: atomic-free scatter from registers.
#pragma unroll
    for (int u = 0; u < PF_EPT; ++u) {
        if (u < nc) {
            unsigned wd = wdv[u];
            srcs[baseL[wd & 255u] + rk[u]] = (int)(wd >> 8);
        }
    }
    int no = min(ovN, PF_OV);
    for (int j = t; j < no; j += PF_T) {
        unsigned wd = ovW[j];
        srcs[baseL[wd & 255u] + ovR[j]] = (int)(wd >> 8);
    }
}

// FUSED layer-1 aggregate + both transforms, 32-node blocks (3125 blocks).
__global__ __launch_bounds__(256) void agg1_t12(
    const _Float16* __restrict__ y, const int* __restrict__ srcs,
    const int* __restrict__ offs, const float* __restrict__ dinv,
    const float* __restrict__ W1, const float* __restrict__ b1,
    const float* __restrict__ W2, _Float16* __restrict__ h2, int n, int E) {
    __shared__ float w1s[320];
    __shared__ float b1s[64];
    __shared__ float w2s[64 * 32];
    __shared__ float o1[32 * 64];
    __shared__ float zs[32 * 6];
    int t = threadIdx.x;
    w1s[t] = W1[t];
    if (t < 64) {
        w1s[t + 256] = W1[t + 256];
        b1s[t] = b1[t];
    }
#pragma unroll
    for (int r = 0; r < 8; ++r) w2s[r * 256 + t] = W2[r * 256 + t];

    int node0 = blockIdx.x * 32;
    int li = t >> 3, e = t & 7;
    int i = node0 + li;
    const half8* yv = (const half8*)y;
    float a0 = 0.f, a1 = 0.f, a2 = 0.f, a3 = 0.f, a4 = 0.f;
    if (i < n) {
        int off = offs[i];
        int cnt = ((i + 1 < n) ? offs[i + 1] : E) - off;
        if (e == 0) {  // self-loop term once per node
            half8 v = yv[i];
            a0 = (float)v[0]; a1 = (float)v[1]; a2 = (float)v[2];
            a3 = (float)v[3]; a4 = (float)v[4];
        }
        for (int p = e; p < cnt; p += 8) {
            half8 v = yv[srcs[off + p]];
            a0 += (float)v[0]; a1 += (float)v[1]; a2 += (float)v[2];
            a3 += (float)v[3]; a4 += (float)v[4];
        }
    }
#pragma unroll
    for (int m = 4; m >= 1; m >>= 1) {
        a0 += __shfl_xor(a0, m, 64);
        a1 += __shfl_xor(a1, m, 64);
        a2 += __shfl_xor(a2, m, 64);
        a3 += __shfl_xor(a3, m, 64);
        a4 += __shfl_xor(a4, m, 64);
    }
    if (i < n && e == 0) {
        float di = dinv[i];
        zs[li * 6 + 0] = a0 * di;
        zs[li * 6 + 1] = a1 * di;
        zs[li * 6 + 2] = a2 * di;
        zs[li * 6 + 3] = a3 * di;
        zs[li * 6 + 4] = a4 * di;
        zs[li * 6 + 5] = di;
    }
    __syncthreads();
#pragma unroll
    for (int r = 0; r < 8; ++r) {
        int idx = r * 256 + t;
        int lj = idx >> 6, f = idx & 63;
        if (node0 + lj < n) {
            const float* zr = zs + lj * 6;
            float acc = b1s[f];
#pragma unroll
            for (int k = 0; k < 5; ++k) acc += zr[k] * w1s[k * 64 + f];
            o1[lj * 64 + f] = fmaxf(acc, 0.0f);
        }
    }
    __syncthreads();
#pragma unroll
    for (int r = 0; r < 4; ++r) {
        int idx = r * 256 + t;
        int lj = idx >> 5, g = idx & 31;
        int i2 = node0 + lj;
        if (i2 < n) {
            float acc = 0.f;
#pragma unroll
            for (int k = 0; k < 64; ++k) acc += o1[lj * 64 + k] * w2s[k * 32 + g];
            h2[(size_t)i2 * 32 + g] = (_Float16)(acc * zs[lj * 6 + 5]);
        }
    }
}

// FUSED layer-2 aggregate + FC head. fp16 h2 rows (64B), 8 threads/node
// each gathering 8B (half4); fp32 accumulation; LDS-staged CSR indices.
__global__ __launch_bounds__(256) void agg2_fc(
    const _Float16* __restrict__ h, const int* __restrict__ srcs,
    const int* __restrict__ offs, const float* __restrict__ dinv,
    const float* __restrict__ b2, const float* __restrict__ fcW1,
    const float* __restrict__ fcb1, const float* __restrict__ fcW2,
    const float* __restrict__ fcb2, float* __restrict__ out, int n, int E) {
    __shared__ int sidx[AGG_STAGE];
    __shared__ float sm[AGG_NODES * 33];
    __shared__ float x3s[AGG_NODES * 16];
    __shared__ float w1s[512];
    __shared__ float w2s[32];
    __shared__ float b1s[16];
    __shared__ float b2s[2];
    __shared__ float bs2[32];
    int t = threadIdx.x;
    w1s[t] = fcW1[t];
    w1s[t + 256] = fcW1[t + 256];
    if (t < 32) { w2s[t] = fcW2[t]; bs2[t] = b2[t]; }
    if (t < 16) b1s[t] = fcb1[t];
    if (t < 2) b2s[t] = fcb2[t];

    int node0 = blockIdx.x * AGG_NODES;
    int li = t >> 3, fq = t & 7;
    int i = node0 + li;
    bool live = (i < n);
    const char* hb = (const char*)h;

    int e0 = offs[node0];
    int eEnd = (node0 + AGG_NODES < n) ? offs[node0 + AGG_NODES] : E;
    int myOff = 0, myCnt = 0;
    float4 acc = {0.f, 0.f, 0.f, 0.f};
    if (live) {
        myOff = offs[i];
        myCnt = ((i + 1 < n) ? offs[i + 1] : E) - myOff;
        half4 sv = *(const half4*)(hb + ((size_t)i << 6) + (fq << 3));
        acc.x = (float)sv.x; acc.y = (float)sv.y;
        acc.z = (float)sv.z; acc.w = (float)sv.w;
    }

    for (int cs = e0; cs < eEnd; cs += AGG_STAGE) {
        int ce = min(cs + AGG_STAGE, eEnd);
        for (int k = cs + t; k < ce; k += 256) sidx[k - cs] = srcs[k] << 6;
        __syncthreads();
        int ps = max(myOff, cs), pe = min(myOff + myCnt, ce);
        int p = ps;
        for (; p + 8 <= pe; p += 8) {
            int o[8];
#pragma unroll
            for (int u = 0; u < 8; ++u) o[u] = sidx[p + u - cs];
            half4 v[8];
#pragma unroll
            for (int u = 0; u < 8; ++u)
                v[u] = *(const half4*)(hb + o[u] + (fq << 3));
#pragma unroll
            for (int u = 0; u < 8; ++u) {
                acc.x += (float)v[u].x; acc.y += (float)v[u].y;
                acc.z += (float)v[u].z; acc.w += (float)v[u].w;
            }
        }
        for (; p + 4 <= pe; p += 4) {
            int o0 = sidx[p - cs], o1 = sidx[p + 1 - cs];
            int o2 = sidx[p + 2 - cs], o3 = sidx[p + 3 - cs];
            half4 v0 = *(const half4*)(hb + o0 + (fq << 3));
            half4 v1 = *(const half4*)(hb + o1 + (fq << 3));
            half4 v2 = *(const half4*)(hb + o2 + (fq << 3));
            half4 v3 = *(const half4*)(hb + o3 + (fq << 3));
            acc.x += (float)v0.x + (float)v1.x + (float)v2.x + (float)v3.x;
            acc.y += (float)v0.y + (float)v1.y + (float)v2.y + (float)v3.y;
            acc.z += (float)v0.z + (float)v1.z + (float)v2.z + (float)v3.z;
            acc.w += (float)v0.w + (float)v1.w + (float)v2.w + (float)v3.w;
        }
        for (; p < pe; ++p) {
            half4 v = *(const half4*)(hb + sidx[p - cs] + (fq << 3));
            acc.x += (float)v.x; acc.y += (float)v.y;
            acc.z += (float)v.z; acc.w += (float)v.w;
        }
        __syncthreads();
    }

    if (live) {
        float di = dinv[i];
        int f0 = fq << 2;
        sm[li * 33 + f0 + 0] = fmaxf(di * acc.x + bs2[f0 + 0], 0.f);
        sm[li * 33 + f0 + 1] = fmaxf(di * acc.y + bs2[f0 + 1], 0.f);
        sm[li * 33 + f0 + 2] = fmaxf(di * acc.z + bs2[f0 + 2], 0.f);
        sm[li * 33 + f0 + 3] = fmaxf(di * acc.w + bs2[f0 + 3], 0.f);
    }
    __syncthreads();
#pragma unroll
    for (int r = 0; r < 2; ++r) {
        int idx = r * 256 + t;
        int lj = idx >> 4, j = idx & 15;
        if (node0 + lj < n) {
            float a = b1s[j];
#pragma unroll
            for (int k = 0; k < 32; ++k) a += sm[lj * 33 + k] * w1s[k * 16 + j];
            x3s[lj * 16 + j] = fmaxf(a, 0.f);
        }
    }
    __syncthreads();
    if (t < 64) {
        int lj = t >> 1, o = t & 1;
        if (node0 + lj < n) {
            float a = b2s[o];
#pragma unroll
            for (int j = 0; j < 16; ++j) a += x3s[lj * 16 + j] * w2s[j * 2 + o];
            out[(size_t)(node0 + lj) * 2 + o] = a;
        }
    }
}

extern "C" void kernel_launch(void* const* d_in, const int* in_sizes, int n_in,
                              void* d_out, int out_size, void* d_ws, size_t ws_size,
                              hipStream_t stream) {
    const float* edge_attr = (const float*)d_in[0];
    const int* edge_index  = (const int*)d_in[1];
    const float* W1   = (const float*)d_in[2];
    const float* b1   = (const float*)d_in[3];
    const float* W2   = (const float*)d_in[4];
    const float* b2   = (const float*)d_in[5];
    const float* fcW1 = (const float*)d_in[6];
    const float* fcb1 = (const float*)d_in[7];
    const float* fcW2 = (const float*)d_in[8];
    const float* fcb2 = (const float*)d_in[9];
    float* out = (float*)d_out;

    int n = in_sizes[0] / 5;
    int E = in_sizes[1] / 2;
    int NBkt = (n + 255) >> 8;                 // 391 for n=100000 (<= MAXB)
    int nTiles = (E + MS_TILE - 1) / MS_TILE;  // 391 at E=1.6M
    const int* src = edge_index;
    const int* dst = edge_index + E;

    char* ws = (char*)d_ws;
    auto alloc = [&](size_t bytes) {
        char* p = ws;
        ws += (bytes + 255) & ~(size_t)255;
        return p;
    };
    int*      offs   = (int*)alloc((size_t)n * 4);
    float*    dinv   = (float*)alloc((size_t)n * 4);
    int*      histG  = (int*)alloc((size_t)nTiles * MAXB * 4);
    int*      offsG  = (int*)alloc((size_t)nTiles * MAXB * 4);
    int*      btot   = (int*)alloc((size_t)MAXB * 4);
    int*      gbase  = (int*)alloc((size_t)(MAXB + 1) * 4);
    int*      srcs   = (int*)alloc((size_t)E * 4);
    unsigned* binned = (unsigned*)alloc((size_t)E * 4);
    _Float16* y      = (_Float16*)alloc((size_t)n * 8 * 2);
    _Float16* h2     = (_Float16*)alloc((size_t)n * 32 * 2);

    histA<<<nTiles, MS_T, 0, stream>>>(dst, histG, E);
    scanTilesT<<<MAXB / 8, 512, 0, stream>>>(histG, offsG, btot, nTiles);
    multisplit2<<<nTiles, MS_T, 0, stream>>>(src, dst, histG, offsG, btot,
                                             gbase, binned, E);
    place_fine2<<<NBkt, PF_T, 0, stream>>>(binned, gbase, edge_attr, offs, dinv,
                                           y, srcs, n);
    agg1_t12<<<(n + 31) / 32, 256, 0, stream>>>(y, srcs, offs, dinv, W1, b1, W2,
                                                h2, n, E);
    agg2_fc<<<(n + AGG_NODES - 1) / AGG_NODES, 256, 0, stream>>>(
        h2, srcs, offs, dinv, b2, fcW1, fcb1, fcW2, fcb2, out, n, E);
}

// Round 7
// 162.685 us; speedup vs baseline: 6.0470x; 1.0644x over previous
//
#include <hip/hip_runtime.h>

// ---------------------------------------------------------------------------
// GCN pipeline, round 31 (= r30 + register-tiled/vectorized W2 phase in
// agg1_t12; everything else byte-identical):
//   histA -> scanTilesT -> multisplit2 -> place_fine2 -> agg1_t12 -> agg2_fc.
// r30 result: 4096-edge tiles gave the session's first win (177->173); sort
// stages are small -- the agg kernels (~40us each, just under the 44us
// top-5 cutoff) dominate. Instruction arithmetic says agg1's o1@W2 phase
// issues ~320-512 wave-wide ds_read instrs per wave (2 scalar LDS reads per
// FMA) on the single per-CU LDS pipe = tens of us serialized. This round:
// thread owns (node j, 4 outputs); per k-quad 5x ds_read_b128 (o1 row
// padded to 68 for 16B alignment + bank spread; w2s rows land on banks
// 0,4..28 conflict-free) = 80 b128/thread vs ~512 b32 -- 3-4x less LDS
// pressure, same fp32 math, coalesced half4 h2 stores.
// ---------------------------------------------------------------------------

#define MS_TILE 4096
#define MS_T 512
#define MAXB 512  // coarse-bucket count (256 nodes each; NBkt=391 <= 512)
#define AGG_NODES 32
#define AGG_STAGE 1024
#define PF_T 512   // place_fine2 threads
#define PF_EPT 10  // cached edges/thread (cap 5120/bucket; mean 4096, sd 64)
#define PF_OV 1024 // LDS spill capacity for the (never-expected) overflow

typedef __attribute__((ext_vector_type(4))) _Float16 half4;
typedef __attribute__((ext_vector_type(8))) _Float16 half8;

// Inclusive shfl scan across 8 waves (512 threads); combine via wsum[8].
__device__ inline int scan512_incl(int v, int lane, int w, int* wsum,
                                   int* total) {
    int incl = v;
#pragma unroll
    for (int d = 1; d < 64; d <<= 1) {
        int up = __shfl_up(incl, d, 64);
        if (lane >= d) incl += up;
    }
    if (lane == 63) wsum[w] = incl;
    __syncthreads();
    int add = 0;
#pragma unroll
    for (int ww = 0; ww < 8; ++ww)
        if (ww < w) add += wsum[ww];
    int tot = 0;
#pragma unroll
    for (int ww = 0; ww < 8; ++ww) tot += wsum[ww];
    *total = tot;
    return incl + add;
}

// per-tile LDS histogram of dst>>8 -> histG[tile*512 + b] (coalesced rows)
__global__ __launch_bounds__(MS_T) void histA(const int* __restrict__ dst,
                                              int* __restrict__ histG, int E) {
    __shared__ int h[MAXB];
    int t = threadIdx.x;
    h[t] = 0;
    __syncthreads();
    int base = blockIdx.x * MS_TILE;
    int cnt = min(MS_TILE, E - base);
    for (int k = t; k < cnt; k += MS_T) atomicAdd(&h[dst[base + k] >> 8], 1);
    __syncthreads();
    histG[blockIdx.x * MAXB + t] = h[t];
}

// Tiled transpose scan: block owns 8 buckets; per 64-tile chunk, load the
// 64x8 sub-panel of histG coalesced, transpose via LDS, shfl-scan each
// bucket in its own wave (register carry), write offsG back coalesced.
__global__ __launch_bounds__(512) void scanTilesT(const int* __restrict__ histG,
                                                  int* __restrict__ offsG,
                                                  int* __restrict__ bucketTotal,
                                                  int nTiles) {
    __shared__ int lds[8][66];
    int t = threadIdx.x;
    int lane = t & 63, w = t >> 6;  // wave w scans bucket B0 + w
    int rr = t >> 3, bb = t & 7;    // load/store mapping (row rr, bucket bb)
    int B0 = blockIdx.x * 8;
    int carry = 0;
    for (int c0 = 0; c0 < nTiles; c0 += 64) {
        int rows = min(64, nTiles - c0);
        int v = 0;
        if (rr < rows) v = histG[(size_t)(c0 + rr) * MAXB + B0 + bb];
        lds[bb][rr] = v;
        __syncthreads();
        int x = lds[w][lane];
        int incl = x;
#pragma unroll
        for (int d = 1; d < 64; d <<= 1) {
            int up = __shfl_up(incl, d, 64);
            if (lane >= d) incl += up;
        }
        int total = __shfl(incl, 63, 64);
        lds[w][lane] = incl - x + carry;  // exclusive prefix + running carry
        carry += total;
        __syncthreads();
        if (rr < rows) offsG[(size_t)(c0 + rr) * MAXB + B0 + bb] = lds[bb][rr];
        __syncthreads();
    }
    if (lane == 0) bucketTotal[B0 + w] = carry;
}

// Deterministic tile counting-sort, 4096-edge tiles @ 512 threads.
// Payload: (src<<8)|(dst&255).
__global__ __launch_bounds__(MS_T) void multisplit2(
    const int* __restrict__ src, const int* __restrict__ dst,
    const int* __restrict__ histG, const int* __restrict__ offsG,
    const int* __restrict__ btot, int* __restrict__ gbaseOut,
    unsigned* __restrict__ binned, int E) {
    __shared__ unsigned stage[MS_TILE];
    __shared__ unsigned short sb[MS_TILE];
    __shared__ int hoff[MAXB + 1];
    __shared__ int hcur[MAXB];
    __shared__ int gb[MAXB];
    __shared__ int wsum[8];
    int t = threadIdx.x;
    int lane = t & 63, w = t >> 6;
    int tile = blockIdx.x;
    int base = tile * MS_TILE;
    int cnt = min(MS_TILE, E - base);

    // bucket-base scan (tile-invariant; one bucket per thread)
    int s2 = btot[t];
    int tot2;
    int incl2 = scan512_incl(s2, lane, w, wsum, &tot2);
    int ex2 = incl2 - s2;
    gb[t] = ex2 + offsG[tile * MAXB + t];
    if (tile == 0) {
        gbaseOut[t] = ex2;
        if (t == MAXB - 1) gbaseOut[MAXB] = E;
    }
    __syncthreads();  // wsum reuse fence

    // tile-local hist scan (one bucket per thread)
    int a0 = histG[tile * MAXB + t];
    int tot;
    int incl = scan512_incl(a0, lane, w, wsum, &tot);
    int ex = incl - a0;
    hoff[t] = ex;
    hcur[t] = ex;
    if (t == MAXB - 1) hoff[MAXB] = cnt;
    __syncthreads();

    for (int k = t; k < cnt; k += MS_T) {
        int d = dst[base + k];
        int b = d >> 8;
        int p = atomicAdd(&hcur[b], 1);
        stage[p] = ((unsigned)src[base + k] << 8) | (unsigned)(d & 255);
        sb[p] = (unsigned short)b;
    }
    __syncthreads();
    for (int k = t; k < cnt; k += MS_T) {
        int b = sb[k];
        binned[gb[b] + (k - hoff[b])] = stage[k];
    }
}

// Per coarse bucket: SINGLE pass over binned (register-cached), first
// atomicAdd doubles as the final intra-node rank. Then shfl scan -> offs,
// dinv, y rows, and an atomic-free register scatter of srcs.
__global__ __launch_bounds__(PF_T) void place_fine2(
    const unsigned* __restrict__ binned, const int* __restrict__ gbase,
    const float* __restrict__ x, int* __restrict__ offs,
    float* __restrict__ dinv, _Float16* __restrict__ y, int* __restrict__ srcs,
    int n) {
    __shared__ int cnt[256];
    __shared__ int baseL[256];
    __shared__ int wsum[8];
    __shared__ unsigned ovW[PF_OV];
    __shared__ int ovR[PF_OV];
    __shared__ int ovN;
    int t = threadIdx.x, b = blockIdx.x;
    int lane = t & 63, w = t >> 6;
    int node0 = b << 8;
    int nn = min(256, n - node0);
    int e0 = gbase[b], e1 = gbase[b + 1];
    if (t < 256) cnt[t] = 0;
    if (t == 0) ovN = 0;
    __syncthreads();

    // pass 1: load + count; the atomic's return value IS the final rank.
    unsigned wdv[PF_EPT];
    int rk[PF_EPT];
    int nc = 0;
#pragma unroll
    for (int u = 0; u < PF_EPT; ++u) {
        int k = e0 + t + u * PF_T;
        if (k < e1) {
            unsigned wd = binned[k];
            wdv[u] = wd;
            rk[u] = atomicAdd(&cnt[wd & 255u], 1);
            nc = u + 1;
        }
    }
    // overflow tail (bucket > PF_EPT*PF_T edges -- never expected; LDS spill)
    for (int k = e0 + t + PF_EPT * PF_T; k < e1; k += PF_T) {
        unsigned wd = binned[k];
        int r = atomicAdd(&cnt[wd & 255u], 1);
        int j = atomicAdd(&ovN, 1);
        if (j < PF_OV) { ovW[j] = wd; ovR[j] = r; }
    }
    __syncthreads();

    // scan counts across the first 4 waves (waves 4..7 carry zeros).
    int c = (t < 256) ? cnt[t] : 0;
    int incl = c;
#pragma unroll
    for (int d = 1; d < 64; d <<= 1) {
        int up = __shfl_up(incl, d, 64);
        if (lane >= d) incl += up;
    }
    if (lane == 63) wsum[w] = incl;
    __syncthreads();
    int add = 0;
    if (w > 0) add += wsum[0];
    if (w > 1) add += wsum[1];
    if (w > 2) add += wsum[2];
    incl += add;
    if (t < 256) {
        int myoff = e0 + incl - c;
        baseL[t] = myoff;
        if (t < nn) {
            int node = node0 + t;
            offs[node] = myoff;
            float di = 1.0f / sqrtf((float)(c + 1));  // +1 self loop
            dinv[node] = di;
            const float* xr = x + (size_t)node * 5;
            half8 hv;
            hv[0] = (_Float16)(xr[0] * di);
            hv[1] = (_Float16)(xr[1] * di);
            hv[2] = (_Float16)(xr[2] * di);
            hv[3] = (_Float16)(xr[3] * di);
            hv[4] = (_Float16)(xr[4] * di);
            hv[5] = (_Float16)0.f;
            hv[6] = (_Float16)0.f;
            hv[7] = (_Float16)0.f;
            *(half8*)(y + (size_t)node * 8) = hv;
        }
    }
    __syncthreads();

    // pass 2: atomic-free scatter from registers.
#pragma unroll
    for (int u = 0; u < PF_EPT; ++u) {
        if (u < nc) {
            unsigned wd = wdv[u];
            srcs[baseL[wd & 255u] + rk[u]] = (int)(wd >> 8);
        }
    }
    int no = min(ovN, PF_OV);
    for (int j = t; j < no; j += PF_T) {
        unsigned wd = ovW[j];
        srcs[baseL[wd & 255u] + ovR[j]] = (int)(wd >> 8);
    }
}

// FUSED layer-1 aggregate + both transforms, 32-node blocks (3125 blocks).
// Gather: 8 threads/node, ONE 16B half8 load per edge, fp32 accumulate,
// shfl-xor reduce; z in LDS. W2 phase: register-tiled (1 node x 4 outputs
// per thread), all-b128 LDS reads, coalesced half4 h2 stores.
__global__ __launch_bounds__(256) void agg1_t12(
    const _Float16* __restrict__ y, const int* __restrict__ srcs,
    const int* __restrict__ offs, const float* __restrict__ dinv,
    const float* __restrict__ W1, const float* __restrict__ b1,
    const float* __restrict__ W2, _Float16* __restrict__ h2, int n, int E) {
    __shared__ float w1s[320];
    __shared__ float b1s[64];
    __shared__ __align__(16) float w2s[64 * 32];  // [k][g] row-major
    __shared__ __align__(16) float o1[32 * 68];   // row padded to 68 floats
    __shared__ float zs[32 * 6];
    int t = threadIdx.x;
    w1s[t] = W1[t];
    if (t < 64) {
        w1s[t + 256] = W1[t + 256];
        b1s[t] = b1[t];
    }
#pragma unroll
    for (int r = 0; r < 8; ++r) w2s[r * 256 + t] = W2[r * 256 + t];

    int node0 = blockIdx.x * 32;
    int li = t >> 3, e = t & 7;
    int i = node0 + li;
    const half8* yv = (const half8*)y;
    float a0 = 0.f, a1 = 0.f, a2 = 0.f, a3 = 0.f, a4 = 0.f;
    if (i < n) {
        int off = offs[i];
        int cnt = ((i + 1 < n) ? offs[i + 1] : E) - off;
        if (e == 0) {  // self-loop term once per node
            half8 v = yv[i];
            a0 = (float)v[0]; a1 = (float)v[1]; a2 = (float)v[2];
            a3 = (float)v[3]; a4 = (float)v[4];
        }
        for (int p = e; p < cnt; p += 8) {
            half8 v = yv[srcs[off + p]];
            a0 += (float)v[0]; a1 += (float)v[1]; a2 += (float)v[2];
            a3 += (float)v[3]; a4 += (float)v[4];
        }
    }
#pragma unroll
    for (int m = 4; m >= 1; m >>= 1) {
        a0 += __shfl_xor(a0, m, 64);
        a1 += __shfl_xor(a1, m, 64);
        a2 += __shfl_xor(a2, m, 64);
        a3 += __shfl_xor(a3, m, 64);
        a4 += __shfl_xor(a4, m, 64);
    }
    if (i < n && e == 0) {
        float di = dinv[i];
        zs[li * 6 + 0] = a0 * di;
        zs[li * 6 + 1] = a1 * di;
        zs[li * 6 + 2] = a2 * di;
        zs[li * 6 + 3] = a3 * di;
        zs[li * 6 + 4] = a4 * di;
        zs[li * 6 + 5] = di;
    }
    __syncthreads();
    // W1 phase: o1[j][f] = relu(z_j . W1[:,f] + b1[f]) into padded rows.
#pragma unroll
    for (int r = 0; r < 8; ++r) {
        int idx = r * 256 + t;
        int lj = idx >> 6, f = idx & 63;
        if (node0 + lj < n) {
            const float* zr = zs + lj * 6;
            float acc = b1s[f];
#pragma unroll
            for (int k = 0; k < 5; ++k) acc += zr[k] * w1s[k * 64 + f];
            o1[lj * 68 + f] = fmaxf(acc, 0.0f);
        }
    }
    __syncthreads();
    // W2 phase: thread = (node j, outputs g0..g0+3). Per k-quad: 1 o1 b128
    // (broadcast across the 8 threads sharing j; banks (4j+k)%32 distinct
    // across j) + 4 w2s b128 (banks 4*gq = 0,4..28 -- conflict-free).
    {
        int j = t >> 3;            // node 0..31
        int g0 = (t & 7) << 2;     // output 0,4,...,28
        const float* o1r = o1 + j * 68;
        float acc0 = 0.f, acc1 = 0.f, acc2 = 0.f, acc3 = 0.f;
#pragma unroll
        for (int k4 = 0; k4 < 64; k4 += 4) {
            float4 ov = *(const float4*)(o1r + k4);
            float4 w0 = *(const float4*)(w2s + (k4 + 0) * 32 + g0);
            float4 w1v = *(const float4*)(w2s + (k4 + 1) * 32 + g0);
            float4 w2v = *(const float4*)(w2s + (k4 + 2) * 32 + g0);
            float4 w3v = *(const float4*)(w2s + (k4 + 3) * 32 + g0);
            acc0 += ov.x * w0.x + ov.y * w1v.x + ov.z * w2v.x + ov.w * w3v.x;
            acc1 += ov.x * w0.y + ov.y * w1v.y + ov.z * w2v.y + ov.w * w3v.y;
            acc2 += ov.x * w0.z + ov.y * w1v.z + ov.z * w2v.z + ov.w * w3v.z;
            acc3 += ov.x * w0.w + ov.y * w1v.w + ov.z * w2v.w + ov.w * w3v.w;
        }
        int i2 = node0 + j;
        if (i2 < n) {
            float di = zs[j * 6 + 5];
            half4 hv;
            hv.x = (_Float16)(acc0 * di);
            hv.y = (_Float16)(acc1 * di);
            hv.z = (_Float16)(acc2 * di);
            hv.w = (_Float16)(acc3 * di);
            *(half4*)(h2 + (size_t)i2 * 32 + g0) = hv;  // coalesced 8B store
        }
    }
}

// FUSED layer-2 aggregate + FC head. fp16 h2 rows (64B), 8 threads/node
// each gathering 8B (half4); fp32 accumulation; LDS-staged CSR indices.
__global__ __launch_bounds__(256) void agg2_fc(
    const _Float16* __restrict__ h, const int* __restrict__ srcs,
    const int* __restrict__ offs, const float* __restrict__ dinv,
    const float* __restrict__ b2, const float* __restrict__ fcW1,
    const float* __restrict__ fcb1, const float* __restrict__ fcW2,
    const float* __restrict__ fcb2, float* __restrict__ out, int n, int E) {
    __shared__ int sidx[AGG_STAGE];
    __shared__ float sm[AGG_NODES * 33];
    __shared__ float x3s[AGG_NODES * 16];
    __shared__ float w1s[512];
    __shared__ float w2s[32];
    __shared__ float b1s[16];
    __shared__ float b2s[2];
    __shared__ float bs2[32];
    int t = threadIdx.x;
    w1s[t] = fcW1[t];
    w1s[t + 256] = fcW1[t + 256];
    if (t < 32) { w2s[t] = fcW2[t]; bs2[t] = b2[t]; }
    if (t < 16) b1s[t] = fcb1[t];
    if (t < 2) b2s[t] = fcb2[t];

    int node0 = blockIdx.x * AGG_NODES;
    int li = t >> 3, fq = t & 7;
    int i = node0 + li;
    bool live = (i < n);
    const char* hb = (const char*)h;

    int e0 = offs[node0];
    int eEnd = (node0 + AGG_NODES < n) ? offs[node0 + AGG_NODES] : E;
    int myOff = 0, myCnt = 0;
    float4 acc = {0.f, 0.f, 0.f, 0.f};
    if (live) {
        myOff = offs[i];
        myCnt = ((i + 1 < n) ? offs[i + 1] : E) - myOff;
        half4 sv = *(const half4*)(hb + ((size_t)i << 6) + (fq << 3));
        acc.x = (float)sv.x; acc.y = (float)sv.y;
        acc.z = (float)sv.z; acc.w = (float)sv.w;
    }

    for (int cs = e0; cs < eEnd; cs += AGG_STAGE) {
        int ce = min(cs + AGG_STAGE, eEnd);
        for (int k = cs + t; k < ce; k += 256) sidx[k - cs] = srcs[k] << 6;
        __syncthreads();
        int ps = max(myOff, cs), pe = min(myOff + myCnt, ce);
        int p = ps;
        for (; p + 8 <= pe; p += 8) {
            int o[8];
#pragma unroll
            for (int u = 0; u < 8; ++u) o[u] = sidx[p + u - cs];
            half4 v[8];
#pragma unroll
            for (int u = 0; u < 8; ++u)
                v[u] = *(const half4*)(hb + o[u] + (fq << 3));
#pragma unroll
            for (int u = 0; u < 8; ++u) {
                acc.x += (float)v[u].x; acc.y += (float)v[u].y;
                acc.z += (float)v[u].z; acc.w += (float)v[u].w;
            }
        }
        for (; p + 4 <= pe; p += 4) {
            int o0 = sidx[p - cs], o1 = sidx[p + 1 - cs];
            int o2 = sidx[p + 2 - cs], o3 = sidx[p + 3 - cs];
            half4 v0 = *(const half4*)(hb + o0 + (fq << 3));
            half4 v1 = *(const half4*)(hb + o1 + (fq << 3));
            half4 v2 = *(const half4*)(hb + o2 + (fq << 3));
            half4 v3 = *(const half4*)(hb + o3 + (fq << 3));
            acc.x += (float)v0.x + (float)v1.x + (float)v2.x + (float)v3.x;
            acc.y += (float)v0.y + (float)v1.y + (float)v2.y + (float)v3.y;
            acc.z += (float)v0.z + (float)v1.z + (float)v2.z + (float)v3.z;
            acc.w += (float)v0.w + (float)v1.w + (float)v2.w + (float)v3.w;
        }
        for (; p < pe; ++p) {
            half4 v = *(const half4*)(hb + sidx[p - cs] + (fq << 3));
            acc.x += (float)v.x; acc.y += (float)v.y;
            acc.z += (float)v.z; acc.w += (float)v.w;
        }
        __syncthreads();
    }

    if (live) {
        float di = dinv[i];
        int f0 = fq << 2;
        sm[li * 33 + f0 + 0] = fmaxf(di * acc.x + bs2[f0 + 0], 0.f);
        sm[li * 33 + f0 + 1] = fmaxf(di * acc.y + bs2[f0 + 1], 0.f);
        sm[li * 33 + f0 + 2] = fmaxf(di * acc.z + bs2[f0 + 2], 0.f);
        sm[li * 33 + f0 + 3] = fmaxf(di * acc.w + bs2[f0 + 3], 0.f);
    }
    __syncthreads();
#pragma unroll
    for (int r = 0; r < 2; ++r) {
        int idx = r * 256 + t;
        int lj = idx >> 4, j = idx & 15;
        if (node0 + lj < n) {
            float a = b1s[j];
#pragma unroll
            for (int k = 0; k < 32; ++k) a += sm[lj * 33 + k] * w1s[k * 16 + j];
            x3s[lj * 16 + j] = fmaxf(a, 0.f);
        }
    }
    __syncthreads();
    if (t < 64) {
        int lj = t >> 1, o = t & 1;
        if (node0 + lj < n) {
            float a = b2s[o];
#pragma unroll
            for (int j = 0; j < 16; ++j) a += x3s[lj * 16 + j] * w2s[j * 2 + o];
            out[(size_t)(node0 + lj) * 2 + o] = a;
        }
    }
}

extern "C" void kernel_launch(void* const* d_in, const int* in_sizes, int n_in,
                              void* d_out, int out_size, void* d_ws, size_t ws_size,
                              hipStream_t stream) {
    const float* edge_attr = (const float*)d_in[0];
    const int* edge_index  = (const int*)d_in[1];
    const float* W1   = (const float*)d_in[2];
    const float* b1   = (const float*)d_in[3];
    const float* W2   = (const float*)d_in[4];
    const float* b2   = (const float*)d_in[5];
    const float* fcW1 = (const float*)d_in[6];
    const float* fcb1 = (const float*)d_in[7];
    const float* fcW2 = (const float*)d_in[8];
    const float* fcb2 = (const float*)d_in[9];
    float* out = (float*)d_out;

    int n = in_sizes[0] / 5;
    int E = in_sizes[1] / 2;
    int NBkt = (n + 255) >> 8;                 // 391 for n=100000 (<= MAXB)
    int nTiles = (E + MS_TILE - 1) / MS_TILE;  // 391 at E=1.6M
    const int* src = edge_index;
    const int* dst = edge_index + E;

    char* ws = (char*)d_ws;
    auto alloc = [&](size_t bytes) {
        char* p = ws;
        ws += (bytes + 255) & ~(size_t)255;
        return p;
    };
    int*      offs   = (int*)alloc((size_t)n * 4);
    float*    dinv   = (float*)alloc((size_t)n * 4);
    int*      histG  = (int*)alloc((size_t)nTiles * MAXB * 4);
    int*      offsG  = (int*)alloc((size_t)nTiles * MAXB * 4);
    int*      btot   = (int*)alloc((size_t)MAXB * 4);
    int*      gbase  = (int*)alloc((size_t)(MAXB + 1) * 4);
    int*      srcs   = (int*)alloc((size_t)E * 4);
    unsigned* binned = (unsigned*)alloc((size_t)E * 4);
    _Float16* y      = (_Float16*)alloc((size_t)n * 8 * 2);
    _Float16* h2     = (_Float16*)alloc((size_t)n * 32 * 2);

    histA<<<nTiles, MS_T, 0, stream>>>(dst, histG, E);
    scanTilesT<<<MAXB / 8, 512, 0, stream>>>(histG, offsG, btot, nTiles);
    multisplit2<<<nTiles, MS_T, 0, stream>>>(src, dst, histG, offsG, btot,
                                             gbase, binned, E);
    place_fine2<<<NBkt, PF_T, 0, stream>>>(binned, gbase, edge_attr, offs, dinv,
                                           y, srcs, n);
    agg1_t12<<<(n + 31) / 32, 256, 0, stream>>>(y, srcs, offs, dinv, W1, b1, W2,
                                                h2, n, E);
    agg2_fc<<<(n + AGG_NODES - 1) / AGG_NODES, 256, 0, stream>>>(
        h2, srcs, offs, dinv, b2, fcW1, fcb1, fcW2, fcb2, out, n, E);
}